// Round 2
// baseline (11566.825 us; speedup 1.0000x reference)
//
#include <hip/hip_runtime.h>
#include <hip/hip_bf16.h>
#include <math.h>

typedef __hip_bfloat16 bf16;
typedef __hip_bfloat162 bf162;

#define D_MODEL 512
#define NUM_HEADS 8
#define HEAD_DIM 64
#define SEQ_LEN 4096
#define BATCH 2
#define D_FF 2048
#define TOKENS (BATCH * SEQ_LEN)

__device__ __forceinline__ float b2f(bf16 v) { return __bfloat162float(v); }
__device__ __forceinline__ bf16 f2b(float v) { return __float2bfloat16(v); }

// ---------------------------------------------------------------------------
// Input dtype detection. flag=1 -> inputs are fp32, flag=0 -> inputs are bf16.
// Look at low 16 bits of each 32-bit word as a bf16: for true bf16 data this
// is a real ~N(0,1) value (exponent field in [110,140] essentially always);
// for fp32 data those bits are mantissa tail -> uniform exponent (~12% hit).
__global__ void detect_kernel(const unsigned int* __restrict__ x, int* __restrict__ flag) {
    __shared__ int cnt;
    if (threadIdx.x == 0) cnt = 0;
    __syncthreads();
    unsigned int w = x[threadIdx.x];
    unsigned int e = (w >> 7) & 0xFFu;  // exponent field of low half as bf16
    if (e >= 110 && e <= 140) atomicAdd(&cnt, 1);
    __syncthreads();
    if (threadIdx.x == 0) flag[0] = (cnt >= (int)(blockDim.x / 2)) ? 0 : 1;
}

// Convert any-dtype input tensor to internal bf16
__global__ void cvt_bf16(const void* __restrict__ src, bf16* __restrict__ dst,
                         int n, const int* __restrict__ flag) {
    int i = blockIdx.x * 256 + threadIdx.x;
    if (i >= n) return;
    dst[i] = (*flag) ? f2b(((const float*)src)[i]) : ((const bf16*)src)[i];
}

// Convert any-dtype input tensor to internal fp32
__global__ void cvt_f32(const void* __restrict__ src, float* __restrict__ dst,
                        int n, const int* __restrict__ flag) {
    int i = blockIdx.x * 256 + threadIdx.x;
    if (i >= n) return;
    dst[i] = (*flag) ? ((const float*)src)[i] : b2f(((const bf16*)src)[i]);
}

// ---------------- LayerNorm: one block (256 threads) per token ----------------
// fp32 input, bf16 params, bf16 output.
__global__ void ln_kernel(const float* __restrict__ x, const bf16* __restrict__ g,
                          const bf16* __restrict__ b, bf16* __restrict__ out) {
    int t = blockIdx.x;
    const float* xr = x + (size_t)t * D_MODEL;
    int tid = threadIdx.x;  // 256 threads, 2 elems each
    float v0 = xr[tid];
    float v1 = xr[tid + 256];
    float s = v0 + v1, ss = v0 * v0 + v1 * v1;
    for (int o = 32; o > 0; o >>= 1) {
        s += __shfl_down(s, o);
        ss += __shfl_down(ss, o);
    }
    __shared__ float rs[4], rss[4], stat[2];
    int w = tid >> 6, l = tid & 63;
    if (l == 0) { rs[w] = s; rss[w] = ss; }
    __syncthreads();
    if (tid == 0) {
        float S = rs[0] + rs[1] + rs[2] + rs[3];
        float SS = rss[0] + rss[1] + rss[2] + rss[3];
        float mu = S / (float)D_MODEL;
        float var = SS / (float)D_MODEL - mu * mu;
        stat[0] = mu;
        stat[1] = rsqrtf(var + 1e-5f);
    }
    __syncthreads();
    float mu = stat[0], rstd = stat[1];
    bf16* orow = out + (size_t)t * D_MODEL;
    orow[tid]       = f2b((v0 - mu) * rstd * b2f(g[tid])       + b2f(b[tid]));
    orow[tid + 256] = f2b((v1 - mu) * rstd * b2f(g[tid + 256]) + b2f(b[tid + 256]));
}

// ---------------- Generic tiled GEMM: C = act(A@W + bias) (+ res) -------------
// A: [M,K] bf16 row-major, W: [K,N] bf16 row-major. 64x64 tile, 256 threads,
// 4x4 micro-tile per thread, BK=16, fp32 accumulation.
// ACT: 0=none, 1=exact GELU. RES: 1 => add res[r*N+c] (fp32 buffer).
// OUTMODE: 0 = bf16 store, 1 = fp32 store, 2 = runtime flag-chosen store.
template <int ACT, int RES, int OUTMODE>
__global__ void gemm_kernel(const bf16* __restrict__ A, const bf16* __restrict__ W,
                            const bf16* __restrict__ bias, const float* __restrict__ res,
                            void* __restrict__ Cout, const int* __restrict__ flag,
                            int M, int N, int K) {
    __shared__ float As[16][68];  // [k][m]
    __shared__ float Ws[16][68];  // [k][n]
    int bx = blockIdx.x, by = blockIdx.y;
    int tid = threadIdx.x;
    int tx = tid & 15, ty = tid >> 4;
    int row0 = by * 64, col0 = bx * 64;
    int fl = (OUTMODE == 2) ? *flag : 0;
    float acc[4][4] = {};

    for (int k0 = 0; k0 < K; k0 += 16) {
        int li = tid * 4;
        int am = li >> 4, ak = li & 15;
        const bf16* ap = A + (size_t)(row0 + am) * K + k0 + ak;
        As[ak + 0][am] = b2f(ap[0]);
        As[ak + 1][am] = b2f(ap[1]);
        As[ak + 2][am] = b2f(ap[2]);
        As[ak + 3][am] = b2f(ap[3]);
        int wk = li >> 6, wn = li & 63;
        const bf16* wp = W + (size_t)(k0 + wk) * N + col0 + wn;
        Ws[wk][wn + 0] = b2f(wp[0]);
        Ws[wk][wn + 1] = b2f(wp[1]);
        Ws[wk][wn + 2] = b2f(wp[2]);
        Ws[wk][wn + 3] = b2f(wp[3]);
        __syncthreads();
#pragma unroll
        for (int kk = 0; kk < 16; kk++) {
            float a[4], w[4];
#pragma unroll
            for (int i = 0; i < 4; i++) a[i] = As[kk][ty * 4 + i];
#pragma unroll
            for (int j = 0; j < 4; j++) w[j] = Ws[kk][tx * 4 + j];
#pragma unroll
            for (int i = 0; i < 4; i++)
#pragma unroll
                for (int j = 0; j < 4; j++) acc[i][j] += a[i] * w[j];
        }
        __syncthreads();
    }

#pragma unroll
    for (int i = 0; i < 4; i++) {
        int r = row0 + ty * 4 + i;
#pragma unroll
        for (int j = 0; j < 4; j++) {
            int c = col0 + tx * 4 + j;
            float v = acc[i][j] + b2f(bias[c]);
            if (ACT == 1) v = 0.5f * v * (1.0f + erff(v * 0.70710678118f));
            if (RES) v += res[(size_t)r * N + c];
            size_t idx = (size_t)r * N + c;
            if (OUTMODE == 0) ((bf16*)Cout)[idx] = f2b(v);
            else if (OUTMODE == 1) ((float*)Cout)[idx] = v;
            else {
                if (fl) ((float*)Cout)[idx] = v;
                else ((bf16*)Cout)[idx] = f2b(v);
            }
        }
    }
}

// ---------------- Attention: one block (256 thr) per (b, h, query row) --------
// Q,K,V in [B*S, D_MODEL] layout; head h occupies contiguous cols [h*64, h*64+64).
__global__ void attn_kernel(const bf16* __restrict__ Q, const bf16* __restrict__ Km,
                            const bf16* __restrict__ V, bf16* __restrict__ O) {
    __shared__ float qs[HEAD_DIM];
    __shared__ float ps[SEQ_LEN];       // 16 KB
    __shared__ float red[8];
    __shared__ float osum[4][HEAD_DIM];

    int bid = blockIdx.x;
    int s = bid & (SEQ_LEN - 1);
    int h = (bid >> 12) & (NUM_HEADS - 1);
    int b = bid >> 15;
    int tid = threadIdx.x;
    size_t base = (size_t)b * SEQ_LEN * D_MODEL + (size_t)h * HEAD_DIM;

    if (tid < HEAD_DIM) qs[tid] = b2f(Q[base + (size_t)s * D_MODEL + tid]) * 0.125f;
    __syncthreads();

    float lmax = -1e30f;
    for (int k = tid; k < SEQ_LEN; k += 256) {
        const bf162* kr = (const bf162*)(Km + base + (size_t)k * D_MODEL);
        float dot = 0.f;
#pragma unroll
        for (int d2 = 0; d2 < HEAD_DIM / 2; d2++) {
            bf162 kv = kr[d2];
            dot += qs[2 * d2] * __low2float(kv) + qs[2 * d2 + 1] * __high2float(kv);
        }
        ps[k] = dot;
        lmax = fmaxf(lmax, dot);
    }
    for (int o = 32; o > 0; o >>= 1) lmax = fmaxf(lmax, __shfl_down(lmax, o));
    int w = tid >> 6, l = tid & 63;
    if (l == 0) red[w] = lmax;
    __syncthreads();
    if (tid == 0) red[0] = fmaxf(fmaxf(red[0], red[1]), fmaxf(red[2], red[3]));
    __syncthreads();
    float m = red[0];

    float lsum = 0.f;
    for (int k = tid; k < SEQ_LEN; k += 256) {
        float p = __expf(ps[k] - m);
        ps[k] = p;
        lsum += p;
    }
    for (int o = 32; o > 0; o >>= 1) lsum += __shfl_down(lsum, o);
    if (l == 0) red[4 + w] = lsum;
    __syncthreads();
    float inv = 1.f / (red[4] + red[5] + red[6] + red[7]);

    int g = tid >> 6, d = tid & 63;
    float acc = 0.f;
    for (int k = g; k < SEQ_LEN; k += 4) {
        acc += ps[k] * b2f(V[base + (size_t)k * D_MODEL + d]);
    }
    osum[g][d] = acc;
    __syncthreads();
    if (g == 0) {
        float v = (osum[0][d] + osum[1][d] + osum[2][d] + osum[3][d]) * inv;
        O[base + (size_t)s * D_MODEL + d] = f2b(v);
    }
}

// ------------------------------------------------------------------------------
extern "C" void kernel_launch(void* const* d_in, const int* in_sizes, int n_in,
                              void* d_out, int out_size, void* d_ws, size_t ws_size,
                              hipStream_t stream) {
    const void* x     = d_in[0];
    const void* Wq    = d_in[1];
    const void* bq    = d_in[2];
    const void* Wk    = d_in[3];
    const void* bk    = d_in[4];
    const void* Wv    = d_in[5];
    const void* bv    = d_in[6];
    const void* Wo    = d_in[7];
    const void* bo    = d_in[8];
    const void* ln1_g = d_in[9];
    const void* ln1_b = d_in[10];
    const void* ln2_g = d_in[11];
    const void* ln2_b = d_in[12];
    const void* W1    = d_in[13];
    const void* b1    = d_in[14];
    const void* W2    = d_in[15];
    const void* b2    = d_in[16];

    // ---- workspace layout ----
    char* p = (char*)d_ws;
    int* flag = (int*)p;                      p += 256;
    size_t tok_d = (size_t)TOKENS * D_MODEL;  // 4,194,304
    float* xf  = (float*)p;                   p += tok_d * 4;       // 16.78 MB
    float* x1f = (float*)p;                   p += tok_d * 4;       // 16.78 MB
    bf16* hb   = (bf16*)p;                    p += tok_d * 2;       // h and h2
    bf16* qb   = (bf16*)p;                    p += tok_d * 2;
    bf16* kb   = (bf16*)p;                    p += tok_d * 2;
    bf16* vb   = (bf16*)p;                    p += tok_d * 2;
    bf16* ab   = (bf16*)p;                    p += tok_d * 2;
    bf16* ffb  = qb;  // reuse q/k/v/attn region (4 * 8.39MB = TOKENS*D_FF*2)
    bf16* Wqb  = (bf16*)p;                    p += (size_t)D_MODEL * D_MODEL * 2;
    bf16* Wkb  = (bf16*)p;                    p += (size_t)D_MODEL * D_MODEL * 2;
    bf16* Wvb  = (bf16*)p;                    p += (size_t)D_MODEL * D_MODEL * 2;
    bf16* Wob  = (bf16*)p;                    p += (size_t)D_MODEL * D_MODEL * 2;
    bf16* W1b  = (bf16*)p;                    p += (size_t)D_MODEL * D_FF * 2;
    bf16* W2b  = (bf16*)p;                    p += (size_t)D_FF * D_MODEL * 2;
    bf16* bqb  = (bf16*)p;                    p += 1024;
    bf16* bkb  = (bf16*)p;                    p += 1024;
    bf16* bvb  = (bf16*)p;                    p += 1024;
    bf16* bob  = (bf16*)p;                    p += 1024;
    bf16* b1b  = (bf16*)p;                    p += D_FF * 2;
    bf16* b2b  = (bf16*)p;                    p += 1024;
    bf16* g1b  = (bf16*)p;                    p += 1024;
    bf16* be1b = (bf16*)p;                    p += 1024;
    bf16* g2b  = (bf16*)p;                    p += 1024;
    bf16* be2b = (bf16*)p;                    p += 1024;

    detect_kernel<<<1, 1024, 0, stream>>>((const unsigned int*)x, flag);

    const int DD = D_MODEL * D_MODEL;         // 262144
    const int DF = D_MODEL * D_FF;            // 1048576
    cvt_bf16<<<DD / 256, 256, 0, stream>>>(Wq, Wqb, DD, flag);
    cvt_bf16<<<DD / 256, 256, 0, stream>>>(Wk, Wkb, DD, flag);
    cvt_bf16<<<DD / 256, 256, 0, stream>>>(Wv, Wvb, DD, flag);
    cvt_bf16<<<DD / 256, 256, 0, stream>>>(Wo, Wob, DD, flag);
    cvt_bf16<<<DF / 256, 256, 0, stream>>>(W1, W1b, DF, flag);
    cvt_bf16<<<DF / 256, 256, 0, stream>>>(W2, W2b, DF, flag);
    cvt_bf16<<<2, 256, 0, stream>>>(bq, bqb, D_MODEL, flag);
    cvt_bf16<<<2, 256, 0, stream>>>(bk, bkb, D_MODEL, flag);
    cvt_bf16<<<2, 256, 0, stream>>>(bv, bvb, D_MODEL, flag);
    cvt_bf16<<<2, 256, 0, stream>>>(bo, bob, D_MODEL, flag);
    cvt_bf16<<<D_FF / 256, 256, 0, stream>>>(b1, b1b, D_FF, flag);
    cvt_bf16<<<2, 256, 0, stream>>>(b2, b2b, D_MODEL, flag);
    cvt_bf16<<<2, 256, 0, stream>>>(ln1_g, g1b, D_MODEL, flag);
    cvt_bf16<<<2, 256, 0, stream>>>(ln1_b, be1b, D_MODEL, flag);
    cvt_bf16<<<2, 256, 0, stream>>>(ln2_g, g2b, D_MODEL, flag);
    cvt_bf16<<<2, 256, 0, stream>>>(ln2_b, be2b, D_MODEL, flag);
    cvt_f32<<<(int)(tok_d / 256), 256, 0, stream>>>(x, xf, (int)tok_d, flag);

    ln_kernel<<<TOKENS, 256, 0, stream>>>(xf, g1b, be1b, hb);

    dim3 g512(D_MODEL / 64, TOKENS / 64);
    gemm_kernel<0, 0, 0><<<g512, 256, 0, stream>>>(hb, Wqb, bqb, nullptr, qb, flag, TOKENS, D_MODEL, D_MODEL);
    gemm_kernel<0, 0, 0><<<g512, 256, 0, stream>>>(hb, Wkb, bkb, nullptr, kb, flag, TOKENS, D_MODEL, D_MODEL);
    gemm_kernel<0, 0, 0><<<g512, 256, 0, stream>>>(hb, Wvb, bvb, nullptr, vb, flag, TOKENS, D_MODEL, D_MODEL);

    attn_kernel<<<BATCH * NUM_HEADS * SEQ_LEN, 256, 0, stream>>>(qb, kb, vb, ab);

    gemm_kernel<0, 1, 1><<<g512, 256, 0, stream>>>(ab, Wob, bob, xf, x1f, flag, TOKENS, D_MODEL, D_MODEL);

    ln_kernel<<<TOKENS, 256, 0, stream>>>(x1f, g2b, be2b, hb);

    dim3 gff(D_FF / 64, TOKENS / 64);
    gemm_kernel<1, 0, 0><<<gff, 256, 0, stream>>>(hb, W1b, b1b, nullptr, ffb, flag, TOKENS, D_FF, D_MODEL);
    gemm_kernel<0, 1, 2><<<g512, 256, 0, stream>>>(ffb, W2b, b2b, x1f, d_out, flag, TOKENS, D_MODEL, D_FF);
}

// Round 3
// 1015.577 us; speedup vs baseline: 11.3894x; 11.3894x over previous
//
#include <hip/hip_runtime.h>
#include <hip/hip_bf16.h>
#include <math.h>

typedef __hip_bfloat16 bf16;
typedef __hip_bfloat162 bf162;

#define D_MODEL 512
#define NUM_HEADS 8
#define HEAD_DIM 64
#define SEQ_LEN 4096
#define BATCH 2
#define D_FF 2048
#define TOKENS (BATCH * SEQ_LEN)

typedef short short4v __attribute__((ext_vector_type(4)));
typedef short short8v __attribute__((ext_vector_type(8)));
typedef float float4v __attribute__((ext_vector_type(4)));

union frag_u { short8v v8; short4v v4[2]; short s[8]; };

__device__ __forceinline__ float b2f(bf16 v) { return __bfloat162float(v); }
__device__ __forceinline__ bf16 f2b(float v) { return __float2bfloat16(v); }

// ---------------------------------------------------------------------------
// Input dtype detection. flag=1 -> inputs are fp32, flag=0 -> inputs are bf16.
__global__ void detect_kernel(const unsigned int* __restrict__ x, int* __restrict__ flag) {
    __shared__ int cnt;
    if (threadIdx.x == 0) cnt = 0;
    __syncthreads();
    unsigned int w = x[threadIdx.x];
    unsigned int e = (w >> 7) & 0xFFu;
    if (e >= 110 && e <= 140) atomicAdd(&cnt, 1);
    __syncthreads();
    if (threadIdx.x == 0) flag[0] = (cnt >= (int)(blockDim.x / 2)) ? 0 : 1;
}

__global__ void cvt_bf16(const void* __restrict__ src, bf16* __restrict__ dst,
                         int n, const int* __restrict__ flag) {
    int i = blockIdx.x * 256 + threadIdx.x;
    if (i >= n) return;
    dst[i] = (*flag) ? f2b(((const float*)src)[i]) : ((const bf16*)src)[i];
}

__global__ void cvt_f32(const void* __restrict__ src, float* __restrict__ dst,
                        int n, const int* __restrict__ flag) {
    int i = blockIdx.x * 256 + threadIdx.x;
    if (i >= n) return;
    dst[i] = (*flag) ? ((const float*)src)[i] : b2f(((const bf16*)src)[i]);
}

// ---------------- LayerNorm: one block (256 threads) per token ----------------
__global__ void ln_kernel(const float* __restrict__ x, const bf16* __restrict__ g,
                          const bf16* __restrict__ b, bf16* __restrict__ out) {
    int t = blockIdx.x;
    const float* xr = x + (size_t)t * D_MODEL;
    int tid = threadIdx.x;
    float v0 = xr[tid];
    float v1 = xr[tid + 256];
    float s = v0 + v1, ss = v0 * v0 + v1 * v1;
    for (int o = 32; o > 0; o >>= 1) {
        s += __shfl_down(s, o);
        ss += __shfl_down(ss, o);
    }
    __shared__ float rs[4], rss[4], stat[2];
    int w = tid >> 6, l = tid & 63;
    if (l == 0) { rs[w] = s; rss[w] = ss; }
    __syncthreads();
    if (tid == 0) {
        float S = rs[0] + rs[1] + rs[2] + rs[3];
        float SS = rss[0] + rss[1] + rss[2] + rss[3];
        float mu = S / (float)D_MODEL;
        float var = SS / (float)D_MODEL - mu * mu;
        stat[0] = mu;
        stat[1] = rsqrtf(var + 1e-5f);
    }
    __syncthreads();
    float mu = stat[0], rstd = stat[1];
    bf16* orow = out + (size_t)t * D_MODEL;
    orow[tid]       = f2b((v0 - mu) * rstd * b2f(g[tid])       + b2f(b[tid]));
    orow[tid + 256] = f2b((v1 - mu) * rstd * b2f(g[tid + 256]) + b2f(b[tid + 256]));
}

// ---------------- Generic tiled GEMM (fp32 VALU, as Round 2) ------------------
template <int ACT, int RES, int OUTMODE>
__global__ void gemm_kernel(const bf16* __restrict__ A, const bf16* __restrict__ W,
                            const bf16* __restrict__ bias, const float* __restrict__ res,
                            void* __restrict__ Cout, const int* __restrict__ flag,
                            int M, int N, int K) {
    __shared__ float As[16][68];
    __shared__ float Ws[16][68];
    int bx = blockIdx.x, by = blockIdx.y;
    int tid = threadIdx.x;
    int tx = tid & 15, ty = tid >> 4;
    int row0 = by * 64, col0 = bx * 64;
    int fl = (OUTMODE == 2) ? *flag : 0;
    float acc[4][4] = {};

    for (int k0 = 0; k0 < K; k0 += 16) {
        int li = tid * 4;
        int am = li >> 4, ak = li & 15;
        const bf16* ap = A + (size_t)(row0 + am) * K + k0 + ak;
        As[ak + 0][am] = b2f(ap[0]);
        As[ak + 1][am] = b2f(ap[1]);
        As[ak + 2][am] = b2f(ap[2]);
        As[ak + 3][am] = b2f(ap[3]);
        int wk = li >> 6, wn = li & 63;
        const bf16* wp = W + (size_t)(k0 + wk) * N + col0 + wn;
        Ws[wk][wn + 0] = b2f(wp[0]);
        Ws[wk][wn + 1] = b2f(wp[1]);
        Ws[wk][wn + 2] = b2f(wp[2]);
        Ws[wk][wn + 3] = b2f(wp[3]);
        __syncthreads();
#pragma unroll
        for (int kk = 0; kk < 16; kk++) {
            float a[4], w[4];
#pragma unroll
            for (int i = 0; i < 4; i++) a[i] = As[kk][ty * 4 + i];
#pragma unroll
            for (int j = 0; j < 4; j++) w[j] = Ws[kk][tx * 4 + j];
#pragma unroll
            for (int i = 0; i < 4; i++)
#pragma unroll
                for (int j = 0; j < 4; j++) acc[i][j] += a[i] * w[j];
        }
        __syncthreads();
    }

#pragma unroll
    for (int i = 0; i < 4; i++) {
        int r = row0 + ty * 4 + i;
#pragma unroll
        for (int j = 0; j < 4; j++) {
            int c = col0 + tx * 4 + j;
            float v = acc[i][j] + b2f(bias[c]);
            if (ACT == 1) v = 0.5f * v * (1.0f + erff(v * 0.70710678118f));
            if (RES) v += res[(size_t)r * N + c];
            size_t idx = (size_t)r * N + c;
            if (OUTMODE == 0) ((bf16*)Cout)[idx] = f2b(v);
            else if (OUTMODE == 1) ((float*)Cout)[idx] = v;
            else {
                if (fl) ((float*)Cout)[idx] = v;
                else ((bf16*)Cout)[idx] = f2b(v);
            }
        }
    }
}

// ---------------- Flash attention with MFMA -----------------------------------
// Grid: (64 q-tiles, 16 bh). Block: 256 thr = 4 waves, each wave owns 16 q rows.
// Q,K,V,O in [B*S, D_MODEL]; head h = contiguous cols [h*64, h*64+64).
// MFMA 16x16x32 bf16. A-layout: A[m=lane&15][k=(lane>>4)*8+j].
// B-layout: B[k=(lane>>4)*8+j][n=lane&15]. C/D: col=lane&15, row=(lane>>4)*4+reg.
__global__ __launch_bounds__(256) void flash_attn(const bf16* __restrict__ Q,
                                                  const bf16* __restrict__ K,
                                                  const bf16* __restrict__ V,
                                                  bf16* __restrict__ O) {
    __shared__ bf16 Ks[64][72];       // [key][dim], pad 72 (row 144 B, 16B-aligned)
    __shared__ bf16 Vt[64][68];       // [dim][key], pad 68 (row 136 B, 8B-aligned)
    __shared__ bf16 Ps[4][16][68];    // per-wave P tile [q_local][key]

    int tid = threadIdx.x;
    int wave = tid >> 6, lane = tid & 63;
    int m = lane & 15, g = lane >> 4;

    int bh = blockIdx.y;
    size_t base = (size_t)(bh >> 3) * SEQ_LEN * D_MODEL + (size_t)(bh & 7) * HEAD_DIM;
    int q0w = blockIdx.x * 64 + wave * 16;

    // Q fragments (A-layout), scale 1/8 folded in (exact pow2 in bf16)
    short8v aQ[2];
    {
        const bf16* qp = Q + base + (size_t)(q0w + m) * D_MODEL + g * 8;
#pragma unroll
        for (int c = 0; c < 2; c++) {
            frag_u u;
#pragma unroll
            for (int j = 0; j < 8; j++) {
                bf16 t = f2b(b2f(qp[c * 32 + j]) * 0.125f);
                u.s[j] = *(short*)&t;
            }
            aQ[c] = u.v8;
        }
    }

    float mold[4] = {-1e30f, -1e30f, -1e30f, -1e30f};
    float lsum[4] = {0.f, 0.f, 0.f, 0.f};
    float4v oacc[4] = {};  // [n-chunk]: dims n*16+m, rows g*4+r

    // staging indices
    int sk = tid >> 2;                 // K: key row
    int sd = (tid & 3) * 16;           // K: dim start
    int vd = tid & 63;                 // V: dim (column)
    int vk = (tid >> 6) * 16;          // V: 16 keys

    const unsigned short* Ku = (const unsigned short*)(K + base);
    const unsigned short* Vu = (const unsigned short*)(V + base);

    for (int kt0 = 0; kt0 < SEQ_LEN; kt0 += 64) {
        __syncthreads();  // previous iteration's reads done
        // stage K tile: row-major
        {
            const unsigned short* kp = Ku + (size_t)(kt0 + sk) * D_MODEL + sd;
            *(short8v*)&Ks[sk][sd]     = *(const short8v*)(kp);
            *(short8v*)&Ks[sk][sd + 8] = *(const short8v*)(kp + 8);
        }
        // stage V tile transposed: Vt[dim][key]
        {
            const unsigned short* vp = Vu + vd;
#pragma unroll
            for (int c = 0; c < 4; c++) {
                short4v pk;
#pragma unroll
                for (int i = 0; i < 4; i++)
                    pk[i] = (short)vp[(size_t)(kt0 + vk + c * 4 + i) * D_MODEL];
                *(short4v*)&Vt[vd][vk + c * 4] = pk;
            }
        }
        __syncthreads();

        // ---- scores: 4 tiles of 16 keys ----
        float4v sc[4];
#pragma unroll
        for (int kt = 0; kt < 4; kt++) {
            short8v bK0 = *(const short8v*)&Ks[kt * 16 + m][g * 8];
            short8v bK1 = *(const short8v*)&Ks[kt * 16 + m][32 + g * 8];
            float4v a = {0.f, 0.f, 0.f, 0.f};
            a = __builtin_amdgcn_mfma_f32_16x16x32_bf16(aQ[0], bK0, a, 0, 0, 0);
            a = __builtin_amdgcn_mfma_f32_16x16x32_bf16(aQ[1], bK1, a, 0, 0, 0);
            sc[kt] = a;
        }

        // ---- online softmax (rows r=0..3 -> q_local g*4+r) ----
        float mnew[4], alpha[4];
#pragma unroll
        for (int r = 0; r < 4; r++) {
            float tm = fmaxf(fmaxf(sc[0][r], sc[1][r]), fmaxf(sc[2][r], sc[3][r]));
#pragma unroll
            for (int off = 1; off < 16; off <<= 1) tm = fmaxf(tm, __shfl_xor(tm, off));
            mnew[r] = fmaxf(mold[r], tm);
            alpha[r] = __expf(mold[r] - mnew[r]);
            mold[r] = mnew[r];
        }
        float tsum[4] = {0.f, 0.f, 0.f, 0.f};
#pragma unroll
        for (int kt = 0; kt < 4; kt++) {
#pragma unroll
            for (int r = 0; r < 4; r++) {
                float p = __expf(sc[kt][r] - mnew[r]);
                tsum[r] += p;
                Ps[wave][g * 4 + r][kt * 16 + m] = f2b(p);
            }
        }
#pragma unroll
        for (int r = 0; r < 4; r++) {
            float t = tsum[r];
#pragma unroll
            for (int off = 1; off < 16; off <<= 1) t += __shfl_xor(t, off);
            lsum[r] = lsum[r] * alpha[r] + t;
        }
#pragma unroll
        for (int n = 0; n < 4; n++)
#pragma unroll
            for (int r = 0; r < 4; r++) oacc[n][r] *= alpha[r];

        // ---- P (A-layout) and PV MFMAs ----
        short8v aP[2];
#pragma unroll
        for (int c = 0; c < 2; c++) {
            frag_u u;
            u.v4[0] = *(const short4v*)&Ps[wave][m][c * 32 + g * 8];
            u.v4[1] = *(const short4v*)&Ps[wave][m][c * 32 + g * 8 + 4];
            aP[c] = u.v8;
        }
#pragma unroll
        for (int n = 0; n < 4; n++) {
#pragma unroll
            for (int c = 0; c < 2; c++) {
                frag_u u;
                u.v4[0] = *(const short4v*)&Vt[n * 16 + m][c * 32 + g * 8];
                u.v4[1] = *(const short4v*)&Vt[n * 16 + m][c * 32 + g * 8 + 4];
                oacc[n] = __builtin_amdgcn_mfma_f32_16x16x32_bf16(aP[c], u.v8, oacc[n], 0, 0, 0);
            }
        }
    }

    // ---- epilogue: O = oacc / l ----
#pragma unroll
    for (int r = 0; r < 4; r++) {
        float inv = 1.f / lsum[r];
        bf16* orow = O + base + (size_t)(q0w + g * 4 + r) * D_MODEL;
#pragma unroll
        for (int n = 0; n < 4; n++) orow[n * 16 + m] = f2b(oacc[n][r] * inv);
    }
}

// ------------------------------------------------------------------------------
extern "C" void kernel_launch(void* const* d_in, const int* in_sizes, int n_in,
                              void* d_out, int out_size, void* d_ws, size_t ws_size,
                              hipStream_t stream) {
    const void* x     = d_in[0];
    const void* Wq    = d_in[1];
    const void* bq    = d_in[2];
    const void* Wk    = d_in[3];
    const void* bk    = d_in[4];
    const void* Wv    = d_in[5];
    const void* bv    = d_in[6];
    const void* Wo    = d_in[7];
    const void* bo    = d_in[8];
    const void* ln1_g = d_in[9];
    const void* ln1_b = d_in[10];
    const void* ln2_g = d_in[11];
    const void* ln2_b = d_in[12];
    const void* W1    = d_in[13];
    const void* b1    = d_in[14];
    const void* W2    = d_in[15];
    const void* b2    = d_in[16];

    // ---- workspace layout ----
    char* p = (char*)d_ws;
    int* flag = (int*)p;                      p += 256;
    size_t tok_d = (size_t)TOKENS * D_MODEL;
    float* xf  = (float*)p;                   p += tok_d * 4;
    float* x1f = (float*)p;                   p += tok_d * 4;
    bf16* hb   = (bf16*)p;                    p += tok_d * 2;
    bf16* qb   = (bf16*)p;                    p += tok_d * 2;
    bf16* kb   = (bf16*)p;                    p += tok_d * 2;
    bf16* vb   = (bf16*)p;                    p += tok_d * 2;
    bf16* ab   = (bf16*)p;                    p += tok_d * 2;
    bf16* ffb  = qb;  // reuse q/k/v/attn region for [TOKENS, D_FF]
    bf16* Wqb  = (bf16*)p;                    p += (size_t)D_MODEL * D_MODEL * 2;
    bf16* Wkb  = (bf16*)p;                    p += (size_t)D_MODEL * D_MODEL * 2;
    bf16* Wvb  = (bf16*)p;                    p += (size_t)D_MODEL * D_MODEL * 2;
    bf16* Wob  = (bf16*)p;                    p += (size_t)D_MODEL * D_MODEL * 2;
    bf16* W1b  = (bf16*)p;                    p += (size_t)D_MODEL * D_FF * 2;
    bf16* W2b  = (bf16*)p;                    p += (size_t)D_FF * D_MODEL * 2;
    bf16* bqb  = (bf16*)p;                    p += 1024;
    bf16* bkb  = (bf16*)p;                    p += 1024;
    bf16* bvb  = (bf16*)p;                    p += 1024;
    bf16* bob  = (bf16*)p;                    p += 1024;
    bf16* b1b  = (bf16*)p;                    p += D_FF * 2;
    bf16* b2b  = (bf16*)p;                    p += 1024;
    bf16* g1b  = (bf16*)p;                    p += 1024;
    bf16* be1b = (bf16*)p;                    p += 1024;
    bf16* g2b  = (bf16*)p;                    p += 1024;
    bf16* be2b = (bf16*)p;                    p += 1024;

    detect_kernel<<<1, 1024, 0, stream>>>((const unsigned int*)x, flag);

    const int DD = D_MODEL * D_MODEL;
    const int DF = D_MODEL * D_FF;
    cvt_bf16<<<DD / 256, 256, 0, stream>>>(Wq, Wqb, DD, flag);
    cvt_bf16<<<DD / 256, 256, 0, stream>>>(Wk, Wkb, DD, flag);
    cvt_bf16<<<DD / 256, 256, 0, stream>>>(Wv, Wvb, DD, flag);
    cvt_bf16<<<DD / 256, 256, 0, stream>>>(Wo, Wob, DD, flag);
    cvt_bf16<<<DF / 256, 256, 0, stream>>>(W1, W1b, DF, flag);
    cvt_bf16<<<DF / 256, 256, 0, stream>>>(W2, W2b, DF, flag);
    cvt_bf16<<<2, 256, 0, stream>>>(bq, bqb, D_MODEL, flag);
    cvt_bf16<<<2, 256, 0, stream>>>(bk, bkb, D_MODEL, flag);
    cvt_bf16<<<2, 256, 0, stream>>>(bv, bvb, D_MODEL, flag);
    cvt_bf16<<<2, 256, 0, stream>>>(bo, bob, D_MODEL, flag);
    cvt_bf16<<<D_FF / 256, 256, 0, stream>>>(b1, b1b, D_FF, flag);
    cvt_bf16<<<2, 256, 0, stream>>>(b2, b2b, D_MODEL, flag);
    cvt_bf16<<<2, 256, 0, stream>>>(ln1_g, g1b, D_MODEL, flag);
    cvt_bf16<<<2, 256, 0, stream>>>(ln1_b, be1b, D_MODEL, flag);
    cvt_bf16<<<2, 256, 0, stream>>>(ln2_g, g2b, D_MODEL, flag);
    cvt_bf16<<<2, 256, 0, stream>>>(ln2_b, be2b, D_MODEL, flag);
    cvt_f32<<<(int)(tok_d / 256), 256, 0, stream>>>(x, xf, (int)tok_d, flag);

    ln_kernel<<<TOKENS, 256, 0, stream>>>(xf, g1b, be1b, hb);

    dim3 g512(D_MODEL / 64, TOKENS / 64);
    gemm_kernel<0, 0, 0><<<g512, 256, 0, stream>>>(hb, Wqb, bqb, nullptr, qb, flag, TOKENS, D_MODEL, D_MODEL);
    gemm_kernel<0, 0, 0><<<g512, 256, 0, stream>>>(hb, Wkb, bkb, nullptr, kb, flag, TOKENS, D_MODEL, D_MODEL);
    gemm_kernel<0, 0, 0><<<g512, 256, 0, stream>>>(hb, Wvb, bvb, nullptr, vb, flag, TOKENS, D_MODEL, D_MODEL);

    flash_attn<<<dim3(64, 16), 256, 0, stream>>>(qb, kb, vb, ab);

    gemm_kernel<0, 1, 1><<<g512, 256, 0, stream>>>(ab, Wob, bob, xf, x1f, flag, TOKENS, D_MODEL, D_MODEL);

    ln_kernel<<<TOKENS, 256, 0, stream>>>(x1f, g2b, be2b, hb);

    dim3 gff(D_FF / 64, TOKENS / 64);
    gemm_kernel<1, 0, 0><<<gff, 256, 0, stream>>>(hb, W1b, b1b, nullptr, ffb, flag, TOKENS, D_FF, D_MODEL);
    gemm_kernel<0, 1, 2><<<g512, 256, 0, stream>>>(ffb, W2b, b2b, x1f, d_out, flag, TOKENS, D_MODEL, D_FF);
}

// Round 4
// 532.371 us; speedup vs baseline: 21.7270x; 1.9076x over previous
//
#include <hip/hip_runtime.h>
#include <hip/hip_bf16.h>
#include <math.h>

typedef __hip_bfloat16 bf16;
typedef __hip_bfloat162 bf162;

#define D_MODEL 512
#define NUM_HEADS 8
#define HEAD_DIM 64
#define SEQ_LEN 4096
#define BATCH 2
#define D_FF 2048
#define TOKENS (BATCH * SEQ_LEN)
#define QKV_STRIDE 1536

typedef short short4v __attribute__((ext_vector_type(4)));
typedef short short8v __attribute__((ext_vector_type(8)));
typedef float float4v __attribute__((ext_vector_type(4)));

union frag_u { short8v v8; short4v v4[2]; short s[8]; };

__device__ __forceinline__ float b2f(bf16 v) { return __bfloat162float(v); }
__device__ __forceinline__ bf16 f2b(float v) { return __float2bfloat16(v); }

#define AS1(p) ((__attribute__((address_space(1))) void*)(p))
#define AS3(p) ((__attribute__((address_space(3))) void*)(p))

// ---------------------------------------------------------------------------
// Input dtype detection. flag=1 -> inputs are fp32, flag=0 -> inputs are bf16.
__global__ void detect_kernel(const unsigned int* __restrict__ x, int* __restrict__ flag) {
    __shared__ int cnt;
    if (threadIdx.x == 0) cnt = 0;
    __syncthreads();
    unsigned int w = x[threadIdx.x];
    unsigned int e = (w >> 7) & 0xFFu;
    if (e >= 110 && e <= 140) atomicAdd(&cnt, 1);
    __syncthreads();
    if (threadIdx.x == 0) flag[0] = (cnt >= (int)(blockDim.x / 2)) ? 0 : 1;
}

__global__ void cvt_bf16(const void* __restrict__ src, bf16* __restrict__ dst,
                         int n, const int* __restrict__ flag) {
    int i = blockIdx.x * 256 + threadIdx.x;
    if (i >= n) return;
    dst[i] = (*flag) ? f2b(((const float*)src)[i]) : ((const bf16*)src)[i];
}

// Transpose-convert: src [K][N] row-major (fp32 or bf16) -> dst [N][K] bf16.
// Grid (N/64, K/64), 256 threads, LDS tile.
__global__ void cvt_transpose(const void* __restrict__ src, bf16* __restrict__ dst,
                              int K, int N, const int* __restrict__ flag) {
    __shared__ bf16 tile[64][65];
    int n0 = blockIdx.x * 64, k0 = blockIdx.y * 64;
    int fl = *flag;
    int c = threadIdx.x & 63, r4 = threadIdx.x >> 6;
#pragma unroll
    for (int t = 0; t < 16; t++) {
        int r = t * 4 + r4;
        size_t si = (size_t)(k0 + r) * N + n0 + c;
        float v = fl ? ((const float*)src)[si] : b2f(((const bf16*)src)[si]);
        tile[r][c] = f2b(v);
    }
    __syncthreads();
#pragma unroll
    for (int t = 0; t < 16; t++) {
        int r = t * 4 + r4;  // r = n-within-tile
        dst[(size_t)(n0 + r) * K + k0 + c] = tile[c][r];
    }
}

// Fused small-vector convert into the params block (see layout in kernel_launch).
__global__ void cvt_small(const void* s0, const void* s1, const void* s2, const void* s3,
                          const void* s4, const void* s5, const void* s6, const void* s7,
                          const void* s8, const void* s9, bf16* __restrict__ dst,
                          const int* __restrict__ flag) {
    int i = blockIdx.x * 256 + threadIdx.x;  // 0..6655
    const void* src; int off;
    if (i < 512)       { src = s0; off = 0; }
    else if (i < 1024) { src = s1; off = 512; }
    else if (i < 1536) { src = s2; off = 1024; }
    else if (i < 2048) { src = s3; off = 1536; }
    else if (i < 4096) { src = s4; off = 2048; }
    else if (i < 4608) { src = s5; off = 4096; }
    else if (i < 5120) { src = s6; off = 4608; }
    else if (i < 5632) { src = s7; off = 5120; }
    else if (i < 6144) { src = s8; off = 5632; }
    else               { src = s9; off = 6144; }
    int j = i - off;
    dst[i] = (*flag) ? f2b(((const float*)src)[j]) : ((const bf16*)src)[j];
}

// ---------------- LayerNorm: one block (256 threads) per token ----------------
// FP32IN: 1 = fp32 input, 0 = bf16 input. Output bf16.
template <int FP32IN>
__global__ void ln_kernel(const void* __restrict__ xv, const bf16* __restrict__ g,
                          const bf16* __restrict__ b, bf16* __restrict__ out) {
    int t = blockIdx.x;
    int tid = threadIdx.x;
    float v0, v1;
    if (FP32IN) {
        const float* xr = (const float*)xv + (size_t)t * D_MODEL;
        v0 = xr[tid]; v1 = xr[tid + 256];
    } else {
        const bf16* xr = (const bf16*)xv + (size_t)t * D_MODEL;
        v0 = b2f(xr[tid]); v1 = b2f(xr[tid + 256]);
    }
    float s = v0 + v1, ss = v0 * v0 + v1 * v1;
    for (int o = 32; o > 0; o >>= 1) {
        s += __shfl_down(s, o);
        ss += __shfl_down(ss, o);
    }
    __shared__ float rs[4], rss[4], stat[2];
    int w = tid >> 6, l = tid & 63;
    if (l == 0) { rs[w] = s; rss[w] = ss; }
    __syncthreads();
    if (tid == 0) {
        float S = rs[0] + rs[1] + rs[2] + rs[3];
        float SS = rss[0] + rss[1] + rss[2] + rss[3];
        float mu = S / (float)D_MODEL;
        float var = SS / (float)D_MODEL - mu * mu;
        stat[0] = mu;
        stat[1] = rsqrtf(var + 1e-5f);
    }
    __syncthreads();
    float mu = stat[0], rstd = stat[1];
    bf16* orow = out + (size_t)t * D_MODEL;
    orow[tid]       = f2b((v0 - mu) * rstd * b2f(g[tid])       + b2f(b[tid]));
    orow[tid + 256] = f2b((v1 - mu) * rstd * b2f(g[tid + 256]) + b2f(b[tid + 256]));
}

// ---------------- MFMA GEMM (m97 structure): C = act(A@W + bias) (+res) ------
// A [M][K] bf16 row-major; Wt [N][K] bf16 row-major (W pre-transposed).
// 128x128 tile, BK=64, 256 thr = 4 waves (2x2 of 64x64), 4x4 MFMA 16x16x32 each.
// ACT: 0 none, 1 tanh-GELU. RES: 0 none, 1 fp32 res, 2 bf16 res.
// OUTMODE: 0 bf16, 1 fp32, 2 flag-chosen.
template <int ACT, int RES, int OUTMODE>
__global__ __launch_bounds__(256) void mfma_gemm(
    const bf16* __restrict__ A, const bf16* __restrict__ Wt,
    const bf16* __restrict__ bias, const float* __restrict__ resf,
    const bf16* __restrict__ resb, void* __restrict__ Cout,
    const int* __restrict__ flag, int M, int N, int K) {
    __shared__ bf16 As[128 * 64];
    __shared__ bf16 Bs[128 * 64];
    int tid = threadIdx.x, wave = tid >> 6, lane = tid & 63;
    int m = lane & 15, g = lane >> 4;
    int row0 = blockIdx.y * 128, col0 = blockIdx.x * 128;
    int R0 = (wave >> 1) * 64, C0 = (wave & 1) * 64;
    int fl = (OUTMODE == 2) ? *flag : 0;
    float4v acc[4][4] = {};

    int srow = lane >> 3;            // 0..7: row within wave's 8-row slab
    int scol = (lane & 7) * 8;       // k-elem offset (16 B)
    const bf16* Ab = A  + (size_t)(row0 + wave * 8 + srow) * K + scol;
    const bf16* Bb = Wt + (size_t)(col0 + wave * 8 + srow) * K + scol;

    for (int k0 = 0; k0 < K; k0 += 64) {
#pragma unroll
        for (int t = 0; t < 4; t++) {
            int rbase = t * 32 + wave * 8;  // wave-uniform LDS slab
            __builtin_amdgcn_global_load_lds(AS1(Ab + (size_t)(t * 32) * K + k0),
                                             AS3(&As[rbase * 64]), 16, 0, 0);
            __builtin_amdgcn_global_load_lds(AS1(Bb + (size_t)(t * 32) * K + k0),
                                             AS3(&Bs[rbase * 64]), 16, 0, 0);
        }
        __syncthreads();
#pragma unroll
        for (int kk = 0; kk < 2; kk++) {
            short8v fa[4], fb[4];
#pragma unroll
            for (int i = 0; i < 4; i++)
                fa[i] = *(const short8v*)&As[(R0 + i * 16 + m) * 64 + kk * 32 + g * 8];
#pragma unroll
            for (int j = 0; j < 4; j++)
                fb[j] = *(const short8v*)&Bs[(C0 + j * 16 + m) * 64 + kk * 32 + g * 8];
#pragma unroll
            for (int i = 0; i < 4; i++)
#pragma unroll
                for (int j = 0; j < 4; j++)
                    acc[i][j] = __builtin_amdgcn_mfma_f32_16x16x32_bf16(fa[i], fb[j], acc[i][j], 0, 0, 0);
        }
        __syncthreads();
    }

#pragma unroll
    for (int i = 0; i < 4; i++) {
#pragma unroll
        for (int r = 0; r < 4; r++) {
            int row = row0 + R0 + i * 16 + g * 4 + r;
#pragma unroll
            for (int j = 0; j < 4; j++) {
                int col = col0 + C0 + j * 16 + m;
                float v = acc[i][j][r] + b2f(bias[col]);
                if (ACT == 1) {
                    // tanh-GELU: v * sigmoid(2 * 0.79788456(v + 0.044715 v^3))
                    float u = 0.7978845608f * (v + 0.044715f * v * v * v);
                    float e2 = __expf(-2.f * u);
                    v = v / (1.f + e2);
                }
                size_t idx = (size_t)row * N + col;
                if (RES == 1) v += resf[idx];
                if (RES == 2) v += b2f(resb[idx]);
                if (OUTMODE == 0) ((bf16*)Cout)[idx] = f2b(v);
                else if (OUTMODE == 1) ((float*)Cout)[idx] = v;
                else {
                    if (fl) ((float*)Cout)[idx] = v;
                    else ((bf16*)Cout)[idx] = f2b(v);
                }
            }
        }
    }
}

// ---------------- Flash attention with MFMA -----------------------------------
// Q,K,V live in the fused qkv buffer [B*S][1536]: Q cols 0-511, K 512-1023,
// V 1024-1535; head h = contiguous 64 cols within each. O written to [B*S][512].
__global__ __launch_bounds__(256) void flash_attn(const bf16* __restrict__ Q,
                                                  const bf16* __restrict__ K,
                                                  const bf16* __restrict__ V,
                                                  bf16* __restrict__ O) {
    __shared__ bf16 Ks[64][72];
    __shared__ bf16 Vt[64][68];
    __shared__ bf16 Ps[4][16][68];

    int tid = threadIdx.x;
    int wave = tid >> 6, lane = tid & 63;
    int m = lane & 15, g = lane >> 4;

    int bh = blockIdx.y;
    size_t base = (size_t)(bh >> 3) * SEQ_LEN * QKV_STRIDE + (size_t)(bh & 7) * HEAD_DIM;
    size_t obase = (size_t)(bh >> 3) * SEQ_LEN * D_MODEL + (size_t)(bh & 7) * HEAD_DIM;
    int q0w = blockIdx.x * 64 + wave * 16;

    short8v aQ[2];
    {
        const bf16* qp = Q + base + (size_t)(q0w + m) * QKV_STRIDE + g * 8;
#pragma unroll
        for (int c = 0; c < 2; c++) {
            frag_u u;
#pragma unroll
            for (int j = 0; j < 8; j++) {
                bf16 t = f2b(b2f(qp[c * 32 + j]) * 0.125f);
                u.s[j] = *(short*)&t;
            }
            aQ[c] = u.v8;
        }
    }

    float mold[4] = {-1e30f, -1e30f, -1e30f, -1e30f};
    float lsum[4] = {0.f, 0.f, 0.f, 0.f};
    float4v oacc[4] = {};

    int sk = tid >> 2;
    int sd = (tid & 3) * 16;
    int vd = tid & 63;
    int vk = (tid >> 6) * 16;

    const unsigned short* Ku = (const unsigned short*)(K + base);
    const unsigned short* Vu = (const unsigned short*)(V + base);

    for (int kt0 = 0; kt0 < SEQ_LEN; kt0 += 64) {
        __syncthreads();
        {
            const unsigned short* kp = Ku + (size_t)(kt0 + sk) * QKV_STRIDE + sd;
            *(short8v*)&Ks[sk][sd]     = *(const short8v*)(kp);
            *(short8v*)&Ks[sk][sd + 8] = *(const short8v*)(kp + 8);
        }
        {
            const unsigned short* vp = Vu + vd;
#pragma unroll
            for (int c = 0; c < 4; c++) {
                short4v pk;
#pragma unroll
                for (int i = 0; i < 4; i++)
                    pk[i] = (short)vp[(size_t)(kt0 + vk + c * 4 + i) * QKV_STRIDE];
                *(short4v*)&Vt[vd][vk + c * 4] = pk;
            }
        }
        __syncthreads();

        float4v sc[4];
#pragma unroll
        for (int kt = 0; kt < 4; kt++) {
            short8v bK0 = *(const short8v*)&Ks[kt * 16 + m][g * 8];
            short8v bK1 = *(const short8v*)&Ks[kt * 16 + m][32 + g * 8];
            float4v a = {0.f, 0.f, 0.f, 0.f};
            a = __builtin_amdgcn_mfma_f32_16x16x32_bf16(aQ[0], bK0, a, 0, 0, 0);
            a = __builtin_amdgcn_mfma_f32_16x16x32_bf16(aQ[1], bK1, a, 0, 0, 0);
            sc[kt] = a;
        }

        float mnew[4], alpha[4];
#pragma unroll
        for (int r = 0; r < 4; r++) {
            float tm = fmaxf(fmaxf(sc[0][r], sc[1][r]), fmaxf(sc[2][r], sc[3][r]));
#pragma unroll
            for (int off = 1; off < 16; off <<= 1) tm = fmaxf(tm, __shfl_xor(tm, off));
            mnew[r] = fmaxf(mold[r], tm);
            alpha[r] = __expf(mold[r] - mnew[r]);
            mold[r] = mnew[r];
        }
        float tsum[4] = {0.f, 0.f, 0.f, 0.f};
#pragma unroll
        for (int kt = 0; kt < 4; kt++) {
#pragma unroll
            for (int r = 0; r < 4; r++) {
                float p = __expf(sc[kt][r] - mnew[r]);
                tsum[r] += p;
                Ps[wave][g * 4 + r][kt * 16 + m] = f2b(p);
            }
        }
#pragma unroll
        for (int r = 0; r < 4; r++) {
            float t = tsum[r];
#pragma unroll
            for (int off = 1; off < 16; off <<= 1) t += __shfl_xor(t, off);
            lsum[r] = lsum[r] * alpha[r] + t;
        }
#pragma unroll
        for (int n = 0; n < 4; n++)
#pragma unroll
            for (int r = 0; r < 4; r++) oacc[n][r] *= alpha[r];

        short8v aP[2];
#pragma unroll
        for (int c = 0; c < 2; c++) {
            frag_u u;
            u.v4[0] = *(const short4v*)&Ps[wave][m][c * 32 + g * 8];
            u.v4[1] = *(const short4v*)&Ps[wave][m][c * 32 + g * 8 + 4];
            aP[c] = u.v8;
        }
#pragma unroll
        for (int n = 0; n < 4; n++) {
#pragma unroll
            for (int c = 0; c < 2; c++) {
                frag_u u;
                u.v4[0] = *(const short4v*)&Vt[n * 16 + m][c * 32 + g * 8];
                u.v4[1] = *(const short4v*)&Vt[n * 16 + m][c * 32 + g * 8 + 4];
                oacc[n] = __builtin_amdgcn_mfma_f32_16x16x32_bf16(aP[c], u.v8, oacc[n], 0, 0, 0);
            }
        }
    }

#pragma unroll
    for (int r = 0; r < 4; r++) {
        float inv = 1.f / lsum[r];
        bf16* orow = O + obase + (size_t)(q0w + g * 4 + r) * D_MODEL;
#pragma unroll
        for (int n = 0; n < 4; n++) orow[n * 16 + m] = f2b(oacc[n][r] * inv);
    }
}

// ------------------------------------------------------------------------------
extern "C" void kernel_launch(void* const* d_in, const int* in_sizes, int n_in,
                              void* d_out, int out_size, void* d_ws, size_t ws_size,
                              hipStream_t stream) {
    const void* x     = d_in[0];
    const void* Wq    = d_in[1];
    const void* bq    = d_in[2];
    const void* Wk    = d_in[3];
    const void* bk    = d_in[4];
    const void* Wv    = d_in[5];
    const void* bv    = d_in[6];
    const void* Wo    = d_in[7];
    const void* bo    = d_in[8];
    const void* ln1_g = d_in[9];
    const void* ln1_b = d_in[10];
    const void* ln2_g = d_in[11];
    const void* ln2_b = d_in[12];
    const void* W1    = d_in[13];
    const void* b1    = d_in[14];
    const void* W2    = d_in[15];
    const void* b2    = d_in[16];

    // ---- workspace layout ----
    char* p = (char*)d_ws;
    int* flag = (int*)p;                      p += 256;
    size_t tok_d = (size_t)TOKENS * D_MODEL;            // 4,194,304
    bf16*  xb   = (bf16*)p;                   p += tok_d * 2;            // 8.39 MB
    float* x1f  = (float*)p;                  p += tok_d * 4;            // 16.78 MB
    bf16*  hb   = (bf16*)p;                   p += tok_d * 2;            // 8.39 MB
    bf16*  bigA = (bf16*)p;                   p += (size_t)TOKENS * D_FF * 2;  // 33.55 MB
    bf16*  qkvb = bigA;                                   // [TOKENS][1536]
    bf16*  ab   = bigA + (size_t)TOKENS * QKV_STRIDE;     // [TOKENS][512]
    bf16*  ffb  = bigA;                                   // [TOKENS][2048] (after ab dead)
    bf16*  Wqkvt = (bf16*)p;                  p += (size_t)QKV_STRIDE * D_MODEL * 2;
    bf16*  Wot   = (bf16*)p;                  p += (size_t)D_MODEL * D_MODEL * 2;
    bf16*  W1t   = (bf16*)p;                  p += (size_t)D_FF * D_MODEL * 2;
    bf16*  W2t   = (bf16*)p;                  p += (size_t)D_MODEL * D_FF * 2;
    bf16*  small = (bf16*)p;                  p += 6656 * 2;
    // params block offsets
    bf16* bias_qkv = small + 0;     // 1536 (bq|bk|bv)
    bf16* bias_o   = small + 1536;  // 512
    bf16* b1b      = small + 2048;  // 2048
    bf16* b2b      = small + 4096;  // 512
    bf16* g1b      = small + 4608;
    bf16* be1b     = small + 5120;
    bf16* g2b      = small + 5632;
    bf16* be2b     = small + 6144;

    detect_kernel<<<1, 1024, 0, stream>>>((const unsigned int*)x, flag);

    cvt_bf16<<<(int)(tok_d / 256), 256, 0, stream>>>(x, xb, (int)tok_d, flag);

    // weight transposes: dst rows are output-cols
    cvt_transpose<<<dim3(8, 8), 256, 0, stream>>>(Wq, Wqkvt,               D_MODEL, D_MODEL, flag);
    cvt_transpose<<<dim3(8, 8), 256, 0, stream>>>(Wk, Wqkvt + 512 * 512,   D_MODEL, D_MODEL, flag);
    cvt_transpose<<<dim3(8, 8), 256, 0, stream>>>(Wv, Wqkvt + 1024 * 512,  D_MODEL, D_MODEL, flag);
    cvt_transpose<<<dim3(8, 8), 256, 0, stream>>>(Wo, Wot,                 D_MODEL, D_MODEL, flag);
    cvt_transpose<<<dim3(32, 8), 256, 0, stream>>>(W1, W1t,                D_MODEL, D_FF, flag);
    cvt_transpose<<<dim3(8, 32), 256, 0, stream>>>(W2, W2t,                D_FF, D_MODEL, flag);

    cvt_small<<<26, 256, 0, stream>>>(bq, bk, bv, bo, b1, b2, ln1_g, ln1_b, ln2_g, ln2_b,
                                      small, flag);

    ln_kernel<0><<<TOKENS, 256, 0, stream>>>(xb, g1b, be1b, hb);

    // fused QKV projection: [8192,512] @ [512,1536]
    mfma_gemm<0, 0, 0><<<dim3(QKV_STRIDE / 128, TOKENS / 128), 256, 0, stream>>>(
        hb, Wqkvt, bias_qkv, nullptr, nullptr, qkvb, flag, TOKENS, QKV_STRIDE, D_MODEL);

    flash_attn<<<dim3(64, 16), 256, 0, stream>>>(qkvb, qkvb + 512, qkvb + 1024, ab);

    // O projection + residual(x) -> x1 (fp32)
    mfma_gemm<0, 2, 1><<<dim3(D_MODEL / 128, TOKENS / 128), 256, 0, stream>>>(
        ab, Wot, bias_o, nullptr, xb, x1f, flag, TOKENS, D_MODEL, D_MODEL);

    ln_kernel<1><<<TOKENS, 256, 0, stream>>>(x1f, g2b, be2b, hb);

    // FFN1 + GELU
    mfma_gemm<1, 0, 0><<<dim3(D_FF / 128, TOKENS / 128), 256, 0, stream>>>(
        hb, W1t, b1b, nullptr, nullptr, ffb, flag, TOKENS, D_FF, D_MODEL);

    // FFN2 + residual(x1) -> out (dtype per flag)
    mfma_gemm<0, 1, 2><<<dim3(D_MODEL / 128, TOKENS / 128), 256, 0, stream>>>(
        ffb, W2t, b2b, x1f, nullptr, d_out, flag, TOKENS, D_MODEL, D_FF);
}

// Round 5
// 485.285 us; speedup vs baseline: 23.8351x; 1.0970x over previous
//
#include <hip/hip_runtime.h>
#include <hip/hip_bf16.h>
#include <math.h>

typedef __hip_bfloat16 bf16;
typedef __hip_bfloat162 bf162;

#define D_MODEL 512
#define NUM_HEADS 8
#define HEAD_DIM 64
#define SEQ_LEN 4096
#define BATCH 2
#define D_FF 2048
#define TOKENS (BATCH * SEQ_LEN)
#define QKV_STRIDE 1536
#define KSPLIT 2

typedef short short4v __attribute__((ext_vector_type(4)));
typedef short short8v __attribute__((ext_vector_type(8)));
typedef float float4v __attribute__((ext_vector_type(4)));

union frag_u { short8v v8; short4v v4[2]; short s[8]; };

__device__ __forceinline__ float b2f(bf16 v) { return __bfloat162float(v); }
__device__ __forceinline__ bf16 f2b(float v) { return __float2bfloat16(v); }

#define AS1(p) ((__attribute__((address_space(1))) void*)(p))
#define AS3(p) ((__attribute__((address_space(3))) void*)(p))

// ---------------------------------------------------------------------------
// Input dtype detection. flag=1 -> inputs are fp32, flag=0 -> inputs are bf16.
__global__ void detect_kernel(const unsigned int* __restrict__ x, int* __restrict__ flag) {
    __shared__ int cnt;
    if (threadIdx.x == 0) cnt = 0;
    __syncthreads();
    unsigned int w = x[threadIdx.x];
    unsigned int e = (w >> 7) & 0xFFu;
    if (e >= 110 && e <= 140) atomicAdd(&cnt, 1);
    __syncthreads();
    if (threadIdx.x == 0) flag[0] = (cnt >= (int)(blockDim.x / 2)) ? 0 : 1;
}

__global__ void cvt_bf16(const void* __restrict__ src, bf16* __restrict__ dst,
                         int n, const int* __restrict__ flag) {
    int i = blockIdx.x * 256 + threadIdx.x;
    if (i >= n) return;
    dst[i] = (*flag) ? f2b(((const float*)src)[i]) : ((const bf16*)src)[i];
}

// Transpose-convert: src [K][N] row-major (fp32 or bf16) -> dst [N][K] bf16.
__global__ void cvt_transpose(const void* __restrict__ src, bf16* __restrict__ dst,
                              int K, int N, const int* __restrict__ flag) {
    __shared__ bf16 tile[64][65];
    int n0 = blockIdx.x * 64, k0 = blockIdx.y * 64;
    int fl = *flag;
    int c = threadIdx.x & 63, r4 = threadIdx.x >> 6;
#pragma unroll
    for (int t = 0; t < 16; t++) {
        int r = t * 4 + r4;
        size_t si = (size_t)(k0 + r) * N + n0 + c;
        float v = fl ? ((const float*)src)[si] : b2f(((const bf16*)src)[si]);
        tile[r][c] = f2b(v);
    }
    __syncthreads();
#pragma unroll
    for (int t = 0; t < 16; t++) {
        int r = t * 4 + r4;
        dst[(size_t)(n0 + r) * K + k0 + c] = tile[c][r];
    }
}

// Four 512x512 transposes in one dispatch (dst blocks contiguous: Wq|Wk|Wv|Wo).
__global__ void cvt_transpose4(const void* s0, const void* s1, const void* s2, const void* s3,
                               bf16* __restrict__ dst, const int* __restrict__ flag) {
    __shared__ bf16 tile[64][65];
    const void* src = (blockIdx.z == 0) ? s0 : (blockIdx.z == 1) ? s1
                    : (blockIdx.z == 2) ? s2 : s3;
    bf16* d = dst + (size_t)blockIdx.z * 512 * 512;
    int n0 = blockIdx.x * 64, k0 = blockIdx.y * 64;
    int fl = *flag;
    int c = threadIdx.x & 63, r4 = threadIdx.x >> 6;
#pragma unroll
    for (int t = 0; t < 16; t++) {
        int r = t * 4 + r4;
        size_t si = (size_t)(k0 + r) * 512 + n0 + c;
        float v = fl ? ((const float*)src)[si] : b2f(((const bf16*)src)[si]);
        tile[r][c] = f2b(v);
    }
    __syncthreads();
#pragma unroll
    for (int t = 0; t < 16; t++) {
        int r = t * 4 + r4;
        d[(size_t)(n0 + r) * 512 + k0 + c] = tile[c][r];
    }
}

// Fused small-vector convert into the params block.
__global__ void cvt_small(const void* s0, const void* s1, const void* s2, const void* s3,
                          const void* s4, const void* s5, const void* s6, const void* s7,
                          const void* s8, const void* s9, bf16* __restrict__ dst,
                          const int* __restrict__ flag) {
    int i = blockIdx.x * 256 + threadIdx.x;  // 0..6655
    const void* src; int off;
    if (i < 512)       { src = s0; off = 0; }
    else if (i < 1024) { src = s1; off = 512; }
    else if (i < 1536) { src = s2; off = 1024; }
    else if (i < 2048) { src = s3; off = 1536; }
    else if (i < 4096) { src = s4; off = 2048; }
    else if (i < 4608) { src = s5; off = 4096; }
    else if (i < 5120) { src = s6; off = 4608; }
    else if (i < 5632) { src = s7; off = 5120; }
    else if (i < 6144) { src = s8; off = 5632; }
    else               { src = s9; off = 6144; }
    int j = i - off;
    dst[i] = (*flag) ? f2b(((const float*)src)[j]) : ((const bf16*)src)[j];
}

// ---------------- LayerNorm: one block (256 threads) per token ----------------
template <int FP32IN>
__global__ void ln_kernel(const void* __restrict__ xv, const bf16* __restrict__ g,
                          const bf16* __restrict__ b, bf16* __restrict__ out) {
    int t = blockIdx.x;
    int tid = threadIdx.x;
    float v0, v1;
    if (FP32IN) {
        const float* xr = (const float*)xv + (size_t)t * D_MODEL;
        v0 = xr[tid]; v1 = xr[tid + 256];
    } else {
        const bf16* xr = (const bf16*)xv + (size_t)t * D_MODEL;
        v0 = b2f(xr[tid]); v1 = b2f(xr[tid + 256]);
    }
    float s = v0 + v1, ss = v0 * v0 + v1 * v1;
    for (int o = 32; o > 0; o >>= 1) {
        s += __shfl_down(s, o);
        ss += __shfl_down(ss, o);
    }
    __shared__ float rs[4], rss[4], stat[2];
    int w = tid >> 6, l = tid & 63;
    if (l == 0) { rs[w] = s; rss[w] = ss; }
    __syncthreads();
    if (tid == 0) {
        float S = rs[0] + rs[1] + rs[2] + rs[3];
        float SS = rss[0] + rss[1] + rss[2] + rss[3];
        float mu = S / (float)D_MODEL;
        float var = SS / (float)D_MODEL - mu * mu;
        stat[0] = mu;
        stat[1] = rsqrtf(var + 1e-5f);
    }
    __syncthreads();
    float mu = stat[0], rstd = stat[1];
    bf16* orow = out + (size_t)t * D_MODEL;
    orow[tid]       = f2b((v0 - mu) * rstd * b2f(g[tid])       + b2f(b[tid]));
    orow[tid + 256] = f2b((v1 - mu) * rstd * b2f(g[tid + 256]) + b2f(b[tid + 256]));
}

// ---------------- MFMA GEMM (m97 structure): C = act(A@W + bias) (+res) ------
template <int ACT, int RES, int OUTMODE>
__global__ __launch_bounds__(256) void mfma_gemm(
    const bf16* __restrict__ A, const bf16* __restrict__ Wt,
    const bf16* __restrict__ bias, const float* __restrict__ resf,
    const bf16* __restrict__ resb, void* __restrict__ Cout,
    const int* __restrict__ flag, int M, int N, int K) {
    __shared__ bf16 As[128 * 64];
    __shared__ bf16 Bs[128 * 64];
    int tid = threadIdx.x, wave = tid >> 6, lane = tid & 63;
    int m = lane & 15, g = lane >> 4;
    int row0 = blockIdx.y * 128, col0 = blockIdx.x * 128;
    int R0 = (wave >> 1) * 64, C0 = (wave & 1) * 64;
    int fl = (OUTMODE == 2) ? *flag : 0;
    float4v acc[4][4] = {};

    int srow = lane >> 3;
    int scol = (lane & 7) * 8;
    const bf16* Ab = A  + (size_t)(row0 + wave * 8 + srow) * K + scol;
    const bf16* Bb = Wt + (size_t)(col0 + wave * 8 + srow) * K + scol;

    for (int k0 = 0; k0 < K; k0 += 64) {
#pragma unroll
        for (int t = 0; t < 4; t++) {
            int rbase = t * 32 + wave * 8;
            __builtin_amdgcn_global_load_lds(AS1(Ab + (size_t)(t * 32) * K + k0),
                                             AS3(&As[rbase * 64]), 16, 0, 0);
            __builtin_amdgcn_global_load_lds(AS1(Bb + (size_t)(t * 32) * K + k0),
                                             AS3(&Bs[rbase * 64]), 16, 0, 0);
        }
        __syncthreads();
#pragma unroll
        for (int kk = 0; kk < 2; kk++) {
            short8v fa[4], fb[4];
#pragma unroll
            for (int i = 0; i < 4; i++)
                fa[i] = *(const short8v*)&As[(R0 + i * 16 + m) * 64 + kk * 32 + g * 8];
#pragma unroll
            for (int j = 0; j < 4; j++)
                fb[j] = *(const short8v*)&Bs[(C0 + j * 16 + m) * 64 + kk * 32 + g * 8];
#pragma unroll
            for (int i = 0; i < 4; i++)
#pragma unroll
                for (int j = 0; j < 4; j++)
                    acc[i][j] = __builtin_amdgcn_mfma_f32_16x16x32_bf16(fa[i], fb[j], acc[i][j], 0, 0, 0);
        }
        __syncthreads();
    }

#pragma unroll
    for (int i = 0; i < 4; i++) {
#pragma unroll
        for (int r = 0; r < 4; r++) {
            int row = row0 + R0 + i * 16 + g * 4 + r;
#pragma unroll
            for (int j = 0; j < 4; j++) {
                int col = col0 + C0 + j * 16 + m;
                float v = acc[i][j][r] + b2f(bias[col]);
                if (ACT == 1) {
                    float u = 0.7978845608f * (v + 0.044715f * v * v * v);
                    float e2 = __expf(-2.f * u);
                    v = v / (1.f + e2);
                }
                size_t idx = (size_t)row * N + col;
                if (RES == 1) v += resf[idx];
                if (RES == 2) v += b2f(resb[idx]);
                if (OUTMODE == 0) ((bf16*)Cout)[idx] = f2b(v);
                else if (OUTMODE == 1) ((float*)Cout)[idx] = v;
                else {
                    if (fl) ((float*)Cout)[idx] = v;
                    else ((bf16*)Cout)[idx] = f2b(v);
                }
            }
        }
    }
}

// ---------------- Flash attention, split-K over keys --------------------------
// Grid (64 q-tiles, 16 bh, KSPLIT). Partials: Op[split][bh][q][d] bf16
// (unnormalized), ml[split][bh][q] = (rowmax, rowsum).
__global__ __launch_bounds__(256) void flash_attn(const bf16* __restrict__ Q,
                                                  const bf16* __restrict__ K,
                                                  const bf16* __restrict__ V,
                                                  bf16* __restrict__ Op,
                                                  float2* __restrict__ mlout) {
    __shared__ bf16 Ks[64][72];
    __shared__ bf16 Vt[64][68];
    __shared__ bf16 Ps[4][16][68];

    int tid = threadIdx.x;
    int wave = tid >> 6, lane = tid & 63;
    int m = lane & 15, g = lane >> 4;

    int bh = blockIdx.y;
    size_t base = (size_t)(bh >> 3) * SEQ_LEN * QKV_STRIDE + (size_t)(bh & 7) * HEAD_DIM;
    int q0w = blockIdx.x * 64 + wave * 16;

    short8v aQ[2];
    {
        const bf16* qp = Q + base + (size_t)(q0w + m) * QKV_STRIDE + g * 8;
#pragma unroll
        for (int c = 0; c < 2; c++) {
            frag_u u;
#pragma unroll
            for (int j = 0; j < 8; j++) {
                bf16 t = f2b(b2f(qp[c * 32 + j]) * 0.125f);
                u.s[j] = *(short*)&t;
            }
            aQ[c] = u.v8;
        }
    }

    float mold[4] = {-1e30f, -1e30f, -1e30f, -1e30f};
    float lsum[4] = {0.f, 0.f, 0.f, 0.f};   // per-lane partial (reduced at end)
    float4v oacc[4] = {};

    int sk = tid >> 2;
    int sd = (tid & 3) * 16;
    int vd = tid & 63;
    int vk = (tid >> 6) * 16;

    const unsigned short* Ku = (const unsigned short*)(K + base);
    const unsigned short* Vu = (const unsigned short*)(V + base);

    int kbeg = blockIdx.z * (SEQ_LEN / KSPLIT);
    int kend = kbeg + SEQ_LEN / KSPLIT;
    for (int kt0 = kbeg; kt0 < kend; kt0 += 64) {
        __syncthreads();
        {
            const unsigned short* kp = Ku + (size_t)(kt0 + sk) * QKV_STRIDE + sd;
            *(short8v*)&Ks[sk][sd]     = *(const short8v*)(kp);
            *(short8v*)&Ks[sk][sd + 8] = *(const short8v*)(kp + 8);
        }
        {
            const unsigned short* vp = Vu + vd;
#pragma unroll
            for (int c = 0; c < 4; c++) {
                short4v pk;
#pragma unroll
                for (int i = 0; i < 4; i++)
                    pk[i] = (short)vp[(size_t)(kt0 + vk + c * 4 + i) * QKV_STRIDE];
                *(short4v*)&Vt[vd][vk + c * 4] = pk;
            }
        }
        __syncthreads();

        float4v sc[4];
#pragma unroll
        for (int kt = 0; kt < 4; kt++) {
            short8v bK0 = *(const short8v*)&Ks[kt * 16 + m][g * 8];
            short8v bK1 = *(const short8v*)&Ks[kt * 16 + m][32 + g * 8];
            float4v a = {0.f, 0.f, 0.f, 0.f};
            a = __builtin_amdgcn_mfma_f32_16x16x32_bf16(aQ[0], bK0, a, 0, 0, 0);
            a = __builtin_amdgcn_mfma_f32_16x16x32_bf16(aQ[1], bK1, a, 0, 0, 0);
            sc[kt] = a;
        }

        float mnew[4], alpha[4];
#pragma unroll
        for (int r = 0; r < 4; r++) {
            float tm = fmaxf(fmaxf(sc[0][r], sc[1][r]), fmaxf(sc[2][r], sc[3][r]));
#pragma unroll
            for (int off = 1; off < 16; off <<= 1) tm = fmaxf(tm, __shfl_xor(tm, off));
            mnew[r] = fmaxf(mold[r], tm);
            alpha[r] = __expf(mold[r] - mnew[r]);
            mold[r] = mnew[r];
        }
#pragma unroll
        for (int kt = 0; kt < 4; kt++) {
#pragma unroll
            for (int r = 0; r < 4; r++) {
                float p = __expf(sc[kt][r] - mnew[r]);
                lsum[r] = (kt == 0) ? lsum[r] * alpha[r] + p : lsum[r] + p;
                Ps[wave][g * 4 + r][kt * 16 + m] = f2b(p);
            }
        }
#pragma unroll
        for (int n = 0; n < 4; n++)
#pragma unroll
            for (int r = 0; r < 4; r++) oacc[n][r] *= alpha[r];

        short8v aP[2];
#pragma unroll
        for (int c = 0; c < 2; c++) {
            frag_u u;
            u.v4[0] = *(const short4v*)&Ps[wave][m][c * 32 + g * 8];
            u.v4[1] = *(const short4v*)&Ps[wave][m][c * 32 + g * 8 + 4];
            aP[c] = u.v8;
        }
#pragma unroll
        for (int n = 0; n < 4; n++) {
#pragma unroll
            for (int c = 0; c < 2; c++) {
                frag_u u;
                u.v4[0] = *(const short4v*)&Vt[n * 16 + m][c * 32 + g * 8];
                u.v4[1] = *(const short4v*)&Vt[n * 16 + m][c * 32 + g * 8 + 4];
                oacc[n] = __builtin_amdgcn_mfma_f32_16x16x32_bf16(aP[c], u.v8, oacc[n], 0, 0, 0);
            }
        }
    }

    // final 16-lane reduce of per-lane l partials
#pragma unroll
    for (int r = 0; r < 4; r++) {
        float t = lsum[r];
#pragma unroll
        for (int off = 1; off < 16; off <<= 1) t += __shfl_xor(t, off);
        lsum[r] = t;
    }

    size_t pbase = ((size_t)blockIdx.z * NUM_HEADS * BATCH + bh) * (SEQ_LEN * (size_t)HEAD_DIM);
#pragma unroll
    for (int r = 0; r < 4; r++) {
        int q = q0w + g * 4 + r;
        bf16* orow = Op + pbase + (size_t)q * HEAD_DIM;
#pragma unroll
        for (int n = 0; n < 4; n++) orow[n * 16 + m] = f2b(oacc[n][r]);
        if (m == 0)
            mlout[((size_t)blockIdx.z * NUM_HEADS * BATCH + bh) * SEQ_LEN + q] =
                make_float2(mold[r], lsum[r]);
    }
}

// Merge 2 split partials -> attention output ab [TOKENS][D_MODEL]
__global__ void attn_merge(const bf16* __restrict__ Op, const float2* __restrict__ ml,
                           bf16* __restrict__ O) {
    int i = blockIdx.x * 256 + threadIdx.x;   // over 16*4096*64
    int d = i & 63;
    int q = (i >> 6) & (SEQ_LEN - 1);
    int bh = i >> 18;
    const int HQ = NUM_HEADS * BATCH * SEQ_LEN;
    float2 a = ml[bh * SEQ_LEN + q];
    float2 b = ml[HQ + bh * SEQ_LEN + q];
    float M = fmaxf(a.x, b.x);
    float w0 = __expf(a.x - M), w1 = __expf(b.x - M);
    float inv = 1.f / (a.y * w0 + b.y * w1);
    const size_t NP = (size_t)HQ * HEAD_DIM;
    float o = (b2f(Op[i]) * w0 + b2f(Op[NP + i]) * w1) * inv;
    O[((size_t)((bh >> 3) * SEQ_LEN + q)) * D_MODEL + (bh & 7) * HEAD_DIM + d] = f2b(o);
}

// ------------------------------------------------------------------------------
extern "C" void kernel_launch(void* const* d_in, const int* in_sizes, int n_in,
                              void* d_out, int out_size, void* d_ws, size_t ws_size,
                              hipStream_t stream) {
    const void* x     = d_in[0];
    const void* Wq    = d_in[1];
    const void* bq    = d_in[2];
    const void* Wk    = d_in[3];
    const void* bk    = d_in[4];
    const void* Wv    = d_in[5];
    const void* bv    = d_in[6];
    const void* Wo    = d_in[7];
    const void* bo    = d_in[8];
    const void* ln1_g = d_in[9];
    const void* ln1_b = d_in[10];
    const void* ln2_g = d_in[11];
    const void* ln2_b = d_in[12];
    const void* W1    = d_in[13];
    const void* b1    = d_in[14];
    const void* W2    = d_in[15];
    const void* b2    = d_in[16];

    // ---- workspace layout ----
    char* p = (char*)d_ws;
    int* flag = (int*)p;                      p += 256;
    size_t tok_d = (size_t)TOKENS * D_MODEL;
    bf16*  xb   = (bf16*)p;                   p += tok_d * 2;            // 8.4 MB
    char*  region2 = p;                       p += tok_d * 4 + tok_d * 2; // x1f+hb, 25.2 MB
    float* x1f  = (float*)region2;
    bf16*  hb   = (bf16*)(region2 + tok_d * 4);
    // split-K partials overlap region2 (dead during flash/merge):
    bf16*   Opart = (bf16*)region2;                                     // 16.78 MB
    float2* mlb   = (float2*)(region2 + (size_t)KSPLIT * NUM_HEADS * BATCH * SEQ_LEN * HEAD_DIM * 2);
    bf16*  bigA = (bf16*)p;                   p += (size_t)TOKENS * D_FF * 2;  // 33.6 MB
    bf16*  qkvb = bigA;                                   // [TOKENS][1536]
    bf16*  ab   = bigA + (size_t)TOKENS * QKV_STRIDE;     // [TOKENS][512]
    bf16*  ffb  = bigA;                                   // [TOKENS][2048]
    bf16*  Wqkvt = (bf16*)p;                  p += (size_t)QKV_STRIDE * D_MODEL * 2;
    bf16*  Wot   = (bf16*)p;                  p += (size_t)D_MODEL * D_MODEL * 2;  // contiguous after Wqkvt
    bf16*  W1t   = (bf16*)p;                  p += (size_t)D_FF * D_MODEL * 2;
    bf16*  W2t   = (bf16*)p;                  p += (size_t)D_MODEL * D_FF * 2;
    bf16*  small = (bf16*)p;                  p += 6656 * 2;
    bf16* bias_qkv = small + 0;
    bf16* bias_o   = small + 1536;
    bf16* b1b      = small + 2048;
    bf16* b2b      = small + 4096;
    bf16* g1b      = small + 4608;
    bf16* be1b     = small + 5120;
    bf16* g2b      = small + 5632;
    bf16* be2b     = small + 6144;

    detect_kernel<<<1, 1024, 0, stream>>>((const unsigned int*)x, flag);

    cvt_bf16<<<(int)(tok_d / 256), 256, 0, stream>>>(x, xb, (int)tok_d, flag);

    // Wq|Wk|Wv|Wo transposes in one dispatch (Wqkvt and Wot contiguous)
    cvt_transpose4<<<dim3(8, 8, 4), 256, 0, stream>>>(Wq, Wk, Wv, Wo, Wqkvt, flag);
    cvt_transpose<<<dim3(32, 8), 256, 0, stream>>>(W1, W1t, D_MODEL, D_FF, flag);
    cvt_transpose<<<dim3(8, 32), 256, 0, stream>>>(W2, W2t, D_FF, D_MODEL, flag);

    cvt_small<<<26, 256, 0, stream>>>(bq, bk, bv, bo, b1, b2, ln1_g, ln1_b, ln2_g, ln2_b,
                                      small, flag);

    ln_kernel<0><<<TOKENS, 256, 0, stream>>>(xb, g1b, be1b, hb);

    // fused QKV projection
    mfma_gemm<0, 0, 0><<<dim3(QKV_STRIDE / 128, TOKENS / 128), 256, 0, stream>>>(
        hb, Wqkvt, bias_qkv, nullptr, nullptr, qkvb, flag, TOKENS, QKV_STRIDE, D_MODEL);

    flash_attn<<<dim3(64, 16, KSPLIT), 256, 0, stream>>>(qkvb, qkvb + 512, qkvb + 1024,
                                                         Opart, mlb);
    attn_merge<<<(NUM_HEADS * BATCH * SEQ_LEN * HEAD_DIM) / 256, 256, 0, stream>>>(
        Opart, mlb, ab);

    // O projection + residual(x) -> x1 (fp32)
    mfma_gemm<0, 2, 1><<<dim3(D_MODEL / 128, TOKENS / 128), 256, 0, stream>>>(
        ab, Wot, bias_o, nullptr, xb, x1f, flag, TOKENS, D_MODEL, D_MODEL);

    ln_kernel<1><<<TOKENS, 256, 0, stream>>>(x1f, g2b, be2b, hb);

    // FFN1 + GELU
    mfma_gemm<1, 0, 0><<<dim3(D_FF / 128, TOKENS / 128), 256, 0, stream>>>(
        hb, W1t, b1b, nullptr, nullptr, ffb, flag, TOKENS, D_FF, D_MODEL);

    // FFN2 + residual(x1) -> out
    mfma_gemm<0, 1, 2><<<dim3(D_MODEL / 128, TOKENS / 128), 256, 0, stream>>>(
        ffb, W2t, b2b, x1f, nullptr, d_out, flag, TOKENS, D_MODEL, D_FF);
}

// Round 6
// 430.131 us; speedup vs baseline: 26.8914x; 1.1282x over previous
//
#include <hip/hip_runtime.h>
#include <hip/hip_bf16.h>
#include <math.h>

typedef __hip_bfloat16 bf16;
typedef __hip_bfloat162 bf162;

#define D_MODEL 512
#define NUM_HEADS 8
#define HEAD_DIM 64
#define SEQ_LEN 4096
#define BATCH 2
#define D_FF 2048
#define TOKENS (BATCH * SEQ_LEN)
#define QKV_STRIDE 1536
#define KSPLIT 2

typedef short short4v __attribute__((ext_vector_type(4)));
typedef short short8v __attribute__((ext_vector_type(8)));
typedef float float4v __attribute__((ext_vector_type(4)));

union frag_u { short8v v8; short4v v4[2]; short s[8]; };

__device__ __forceinline__ float b2f(bf16 v) { return __bfloat162float(v); }
__device__ __forceinline__ bf16 f2b(float v) { return __float2bfloat16(v); }
__device__ __forceinline__ short f2bs(float v) { bf16 t = __float2bfloat16(v); return *(short*)&t; }

#define AS1(p) ((__attribute__((address_space(1))) void*)(p))
#define AS3(p) ((__attribute__((address_space(3))) void*)(p))

// ---------------------------------------------------------------------------
// Input dtype detection. flag=1 -> inputs are fp32, flag=0 -> inputs are bf16.
__global__ void detect_kernel(const unsigned int* __restrict__ x, int* __restrict__ flag) {
    __shared__ int cnt;
    if (threadIdx.x == 0) cnt = 0;
    __syncthreads();
    unsigned int w = x[threadIdx.x];
    unsigned int e = (w >> 7) & 0xFFu;
    if (e >= 110 && e <= 140) atomicAdd(&cnt, 1);
    __syncthreads();
    if (threadIdx.x == 0) flag[0] = (cnt >= (int)(blockDim.x / 2)) ? 0 : 1;
}

// Transpose-convert: src [K][N] row-major (fp32 or bf16) -> dst [N][K] bf16.
__global__ void cvt_transpose(const void* __restrict__ src, bf16* __restrict__ dst,
                              int K, int N, const int* __restrict__ flag) {
    __shared__ bf16 tile[64][65];
    int n0 = blockIdx.x * 64, k0 = blockIdx.y * 64;
    int fl = *flag;
    int c = threadIdx.x & 63, r4 = threadIdx.x >> 6;
#pragma unroll
    for (int t = 0; t < 16; t++) {
        int r = t * 4 + r4;
        size_t si = (size_t)(k0 + r) * N + n0 + c;
        float v = fl ? ((const float*)src)[si] : b2f(((const bf16*)src)[si]);
        tile[r][c] = f2b(v);
    }
    __syncthreads();
#pragma unroll
    for (int t = 0; t < 16; t++) {
        int r = t * 4 + r4;
        dst[(size_t)(n0 + r) * K + k0 + c] = tile[c][r];
    }
}

// Four 512x512 transposes in one dispatch (dst blocks contiguous: Wq|Wk|Wv|Wo).
__global__ void cvt_transpose4(const void* s0, const void* s1, const void* s2, const void* s3,
                               bf16* __restrict__ dst, const int* __restrict__ flag) {
    __shared__ bf16 tile[64][65];
    const void* src = (blockIdx.z == 0) ? s0 : (blockIdx.z == 1) ? s1
                    : (blockIdx.z == 2) ? s2 : s3;
    bf16* d = dst + (size_t)blockIdx.z * 512 * 512;
    int n0 = blockIdx.x * 64, k0 = blockIdx.y * 64;
    int fl = *flag;
    int c = threadIdx.x & 63, r4 = threadIdx.x >> 6;
#pragma unroll
    for (int t = 0; t < 16; t++) {
        int r = t * 4 + r4;
        size_t si = (size_t)(k0 + r) * 512 + n0 + c;
        float v = fl ? ((const float*)src)[si] : b2f(((const bf16*)src)[si]);
        tile[r][c] = f2b(v);
    }
    __syncthreads();
#pragma unroll
    for (int t = 0; t < 16; t++) {
        int r = t * 4 + r4;
        d[(size_t)(n0 + r) * 512 + k0 + c] = tile[c][r];
    }
}

// Fused small-vector convert into the params block.
__global__ void cvt_small(const void* s0, const void* s1, const void* s2, const void* s3,
                          const void* s4, const void* s5, const void* s6, const void* s7,
                          const void* s8, const void* s9, bf16* __restrict__ dst,
                          const int* __restrict__ flag) {
    int i = blockIdx.x * 256 + threadIdx.x;  // 0..6655
    const void* src; int off;
    if (i < 512)       { src = s0; off = 0; }
    else if (i < 1024) { src = s1; off = 512; }
    else if (i < 1536) { src = s2; off = 1024; }
    else if (i < 2048) { src = s3; off = 1536; }
    else if (i < 4096) { src = s4; off = 2048; }
    else if (i < 4608) { src = s5; off = 4096; }
    else if (i < 5120) { src = s6; off = 4608; }
    else if (i < 5632) { src = s7; off = 5120; }
    else if (i < 6144) { src = s8; off = 5632; }
    else               { src = s9; off = 6144; }
    int j = i - off;
    dst[i] = (*flag) ? f2b(((const float*)src)[j]) : ((const bf16*)src)[j];
}

// ---------------- LayerNorm: one block (256 threads) per token ----------------
// MODE: 0 = bf16 input, 1 = fp32 input, 2 = flag-chosen raw input.
template <int MODE>
__global__ void ln_kernel(const void* __restrict__ xv, const bf16* __restrict__ g,
                          const bf16* __restrict__ b, bf16* __restrict__ out,
                          const int* __restrict__ flag) {
    int t = blockIdx.x;
    int tid = threadIdx.x;
    int fl = (MODE == 2) ? *flag : (MODE == 1);
    float v0, v1;
    if (fl) {
        const float* xr = (const float*)xv + (size_t)t * D_MODEL;
        v0 = xr[tid]; v1 = xr[tid + 256];
    } else {
        const bf16* xr = (const bf16*)xv + (size_t)t * D_MODEL;
        v0 = b2f(xr[tid]); v1 = b2f(xr[tid + 256]);
    }
    float s = v0 + v1, ss = v0 * v0 + v1 * v1;
    for (int o = 32; o > 0; o >>= 1) {
        s += __shfl_down(s, o);
        ss += __shfl_down(ss, o);
    }
    __shared__ float rs[4], rss[4], stat[2];
    int w = tid >> 6, l = tid & 63;
    if (l == 0) { rs[w] = s; rss[w] = ss; }
    __syncthreads();
    if (tid == 0) {
        float S = rs[0] + rs[1] + rs[2] + rs[3];
        float SS = rss[0] + rss[1] + rss[2] + rss[3];
        float mu = S / (float)D_MODEL;
        float var = SS / (float)D_MODEL - mu * mu;
        stat[0] = mu;
        stat[1] = rsqrtf(var + 1e-5f);
    }
    __syncthreads();
    float mu = stat[0], rstd = stat[1];
    bf16* orow = out + (size_t)t * D_MODEL;
    orow[tid]       = f2b((v0 - mu) * rstd * b2f(g[tid])       + b2f(b[tid]));
    orow[tid + 256] = f2b((v1 - mu) * rstd * b2f(g[tid + 256]) + b2f(b[tid + 256]));
}

__device__ __forceinline__ float gelu_tanh(float v) {
    float u = 0.7978845608f * (v + 0.044715f * v * v * v);
    float e2 = __expf(-2.f * u);
    return v / (1.f + e2);
}

// ---------------- MFMA GEMM 128x128 (m97 structure) ---------------------------
// ACT: 0 none, 1 tanh-GELU. RES: 0 none. OUTMODE: 0 bf16.
template <int ACT, int OUTMODE>
__global__ __launch_bounds__(256) void mfma_gemm(
    const bf16* __restrict__ A, const bf16* __restrict__ Wt,
    const bf16* __restrict__ bias, void* __restrict__ Cout,
    const int* __restrict__ flag, int M, int N, int K) {
    __shared__ bf16 As[128 * 64];
    __shared__ bf16 Bs[128 * 64];
    int tid = threadIdx.x, wave = tid >> 6, lane = tid & 63;
    int m = lane & 15, g = lane >> 4;
    int row0 = blockIdx.y * 128, col0 = blockIdx.x * 128;
    int R0 = (wave >> 1) * 64, C0 = (wave & 1) * 64;
    float4v acc[4][4] = {};

    int srow = lane >> 3;
    int scol = (lane & 7) * 8;
    const bf16* Ab = A  + (size_t)(row0 + wave * 8 + srow) * K + scol;
    const bf16* Bb = Wt + (size_t)(col0 + wave * 8 + srow) * K + scol;

    for (int k0 = 0; k0 < K; k0 += 64) {
#pragma unroll
        for (int t = 0; t < 4; t++) {
            int rbase = t * 32 + wave * 8;
            __builtin_amdgcn_global_load_lds(AS1(Ab + (size_t)(t * 32) * K + k0),
                                             AS3(&As[rbase * 64]), 16, 0, 0);
            __builtin_amdgcn_global_load_lds(AS1(Bb + (size_t)(t * 32) * K + k0),
                                             AS3(&Bs[rbase * 64]), 16, 0, 0);
        }
        __syncthreads();
#pragma unroll
        for (int kk = 0; kk < 2; kk++) {
            short8v fa[4], fb[4];
#pragma unroll
            for (int i = 0; i < 4; i++)
                fa[i] = *(const short8v*)&As[(R0 + i * 16 + m) * 64 + kk * 32 + g * 8];
#pragma unroll
            for (int j = 0; j < 4; j++)
                fb[j] = *(const short8v*)&Bs[(C0 + j * 16 + m) * 64 + kk * 32 + g * 8];
#pragma unroll
            for (int i = 0; i < 4; i++)
#pragma unroll
                for (int j = 0; j < 4; j++)
                    acc[i][j] = __builtin_amdgcn_mfma_f32_16x16x32_bf16(fa[i], fb[j], acc[i][j], 0, 0, 0);
        }
        __syncthreads();
    }

#pragma unroll
    for (int i = 0; i < 4; i++) {
#pragma unroll
        for (int r = 0; r < 4; r++) {
            int row = row0 + R0 + i * 16 + g * 4 + r;
#pragma unroll
            for (int j = 0; j < 4; j++) {
                int col = col0 + C0 + j * 16 + m;
                float v = acc[i][j][r] + b2f(bias[col]);
                if (ACT == 1) v = gelu_tanh(v);
                size_t idx = (size_t)row * N + col;
                ((bf16*)Cout)[idx] = f2b(v);
            }
        }
    }
}

// ---------------- MFMA GEMM 128x64 tile (for N=512: 512 blocks) ---------------
// RES: 1 fp32 res, 3 raw-input res (dtype per flag). OUTMODE: 1 fp32, 2 flag.
template <int RES, int OUTMODE>
__global__ __launch_bounds__(256) void mfma_gemm64(
    const bf16* __restrict__ A, const bf16* __restrict__ Wt,
    const bf16* __restrict__ bias, const float* __restrict__ resf,
    const void* __restrict__ resraw, void* __restrict__ Cout,
    const int* __restrict__ flag, int M, int N, int K) {
    __shared__ bf16 As[128 * 64];
    __shared__ bf16 Bs[64 * 64];
    int tid = threadIdx.x, wave = tid >> 6, lane = tid & 63;
    int m = lane & 15, g = lane >> 4;
    int row0 = blockIdx.y * 128, col0 = blockIdx.x * 64;
    int R0 = wave * 32;
    int fl = (OUTMODE == 2 || RES == 3) ? *flag : 0;
    float4v acc[2][4] = {};

    int srow = lane >> 3;
    int scol = (lane & 7) * 8;
    const bf16* Ab = A  + (size_t)(row0 + wave * 8 + srow) * K + scol;
    const bf16* Bb = Wt + (size_t)(col0 + wave * 8 + srow) * K + scol;

    for (int k0 = 0; k0 < K; k0 += 64) {
#pragma unroll
        for (int t = 0; t < 4; t++) {
            __builtin_amdgcn_global_load_lds(AS1(Ab + (size_t)(t * 32) * K + k0),
                                             AS3(&As[(t * 32 + wave * 8) * 64]), 16, 0, 0);
            if (t < 2)
                __builtin_amdgcn_global_load_lds(AS1(Bb + (size_t)(t * 32) * K + k0),
                                                 AS3(&Bs[(t * 32 + wave * 8) * 64]), 16, 0, 0);
        }
        __syncthreads();
#pragma unroll
        for (int kk = 0; kk < 2; kk++) {
            short8v fa[2], fb[4];
#pragma unroll
            for (int i = 0; i < 2; i++)
                fa[i] = *(const short8v*)&As[(R0 + i * 16 + m) * 64 + kk * 32 + g * 8];
#pragma unroll
            for (int j = 0; j < 4; j++)
                fb[j] = *(const short8v*)&Bs[(j * 16 + m) * 64 + kk * 32 + g * 8];
#pragma unroll
            for (int i = 0; i < 2; i++)
#pragma unroll
                for (int j = 0; j < 4; j++)
                    acc[i][j] = __builtin_amdgcn_mfma_f32_16x16x32_bf16(fa[i], fb[j], acc[i][j], 0, 0, 0);
        }
        __syncthreads();
    }

#pragma unroll
    for (int i = 0; i < 2; i++) {
#pragma unroll
        for (int r = 0; r < 4; r++) {
            int row = row0 + R0 + i * 16 + g * 4 + r;
#pragma unroll
            for (int j = 0; j < 4; j++) {
                int col = col0 + j * 16 + m;
                float v = acc[i][j][r] + b2f(bias[col]);
                size_t idx = (size_t)row * N + col;
                if (RES == 1) v += resf[idx];
                if (RES == 3) v += fl ? ((const float*)resraw)[idx]
                                      : b2f(((const bf16*)resraw)[idx]);
                if (OUTMODE == 1) ((float*)Cout)[idx] = v;
                else {
                    if (fl) ((float*)Cout)[idx] = v;
                    else ((bf16*)Cout)[idx] = f2b(v);
                }
            }
        }
    }
}

// ---------------- Flash attention, S^T formulation, split-K -------------------
// Scores computed transposed: St = K·Q^T (C-layout: col=q, row=k) so each lane
// owns ONE q-row -> reductions are 2 quad-shuffles; P^T is k-contiguous per
// lane -> 4 ds_write_b64 + 2 ds_read_b128 round-trip. PV: O^T = V^T·P^T.
__global__ __launch_bounds__(256) void flash_attn(const bf16* __restrict__ Q,
                                                  const bf16* __restrict__ K,
                                                  const bf16* __restrict__ V,
                                                  bf16* __restrict__ Op,
                                                  float2* __restrict__ mlout) {
    __shared__ bf16 Ks[64][72];
    __shared__ bf16 Vt[64][68];
    __shared__ bf16 Pt[4][16][72];   // per-wave P^T as [q=m][k], pitch 72

    int tid = threadIdx.x;
    int wave = tid >> 6, lane = tid & 63;
    int m = lane & 15, g = lane >> 4;

    int bh = blockIdx.y;
    size_t base = (size_t)(bh >> 3) * SEQ_LEN * QKV_STRIDE + (size_t)(bh & 7) * HEAD_DIM;
    int q0w = blockIdx.x * 64 + wave * 16;

    // Q fragment (B-operand of St): lane holds Q[q0w+m][c*32+g*8+j] * 0.125
    short8v aQ[2];
    {
        const bf16* qp = Q + base + (size_t)(q0w + m) * QKV_STRIDE + g * 8;
#pragma unroll
        for (int c = 0; c < 2; c++) {
            frag_u u;
#pragma unroll
            for (int j = 0; j < 8; j++) u.s[j] = f2bs(b2f(qp[c * 32 + j]) * 0.125f);
            aQ[c] = u.v8;
        }
    }

    float mrow = -1e30f, lrow = 0.f;   // this lane's q = q0w + m
    float4v oacc[4] = {};              // O^T: [dtile]: d = dt*16+g*4+r, q = m

    int sk = tid >> 2;
    int sd = (tid & 3) * 16;
    int vd = tid & 63;
    int vk = (tid >> 6) * 16;

    const unsigned short* Ku = (const unsigned short*)(K + base);
    const unsigned short* Vu = (const unsigned short*)(V + base);

    int kbeg = blockIdx.z * (SEQ_LEN / KSPLIT);
    int kend = kbeg + SEQ_LEN / KSPLIT;
    for (int kt0 = kbeg; kt0 < kend; kt0 += 64) {
        __syncthreads();
        {
            const unsigned short* kp = Ku + (size_t)(kt0 + sk) * QKV_STRIDE + sd;
            *(short8v*)&Ks[sk][sd]     = *(const short8v*)(kp);
            *(short8v*)&Ks[sk][sd + 8] = *(const short8v*)(kp + 8);
        }
        {
            const unsigned short* vp = Vu + vd;
#pragma unroll
            for (int c = 0; c < 4; c++) {
                short4v pk;
#pragma unroll
                for (int i = 0; i < 4; i++)
                    pk[i] = (short)vp[(size_t)(kt0 + vk + c * 4 + i) * QKV_STRIDE];
                *(short4v*)&Vt[vd][vk + c * 4] = pk;
            }
        }
        __syncthreads();

        // St[kt]: lane reg r = score(q = q0w+m, k = kt0 + kt*16 + g*4 + r)
        float4v st[4];
#pragma unroll
        for (int kt = 0; kt < 4; kt++) {
            short8v bK0 = *(const short8v*)&Ks[kt * 16 + m][g * 8];
            short8v bK1 = *(const short8v*)&Ks[kt * 16 + m][32 + g * 8];
            float4v a = {0.f, 0.f, 0.f, 0.f};
            a = __builtin_amdgcn_mfma_f32_16x16x32_bf16(bK0, aQ[0], a, 0, 0, 0);
            a = __builtin_amdgcn_mfma_f32_16x16x32_bf16(bK1, aQ[1], a, 0, 0, 0);
            st[kt] = a;
        }

        // online softmax: all 16 scores belong to q = q0w+m
        float tm = st[0][0];
#pragma unroll
        for (int kt = 0; kt < 4; kt++)
#pragma unroll
            for (int r = 0; r < 4; r++) tm = fmaxf(tm, st[kt][r]);
        tm = fmaxf(tm, __shfl_xor(tm, 16));
        tm = fmaxf(tm, __shfl_xor(tm, 32));
        float mnew = fmaxf(mrow, tm);
        float alpha = __expf(mrow - mnew);
        mrow = mnew;

        float psum = 0.f;
#pragma unroll
        for (int kt = 0; kt < 4; kt++) {
            float p0 = __expf(st[kt][0] - mnew);
            float p1 = __expf(st[kt][1] - mnew);
            float p2 = __expf(st[kt][2] - mnew);
            float p3 = __expf(st[kt][3] - mnew);
            psum += (p0 + p1) + (p2 + p3);
            short4v pk = {f2bs(p0), f2bs(p1), f2bs(p2), f2bs(p3)};
            *(short4v*)&Pt[wave][m][kt * 16 + g * 4] = pk;
        }
        lrow = lrow * alpha + psum;
#pragma unroll
        for (int dt = 0; dt < 4; dt++)
#pragma unroll
            for (int r = 0; r < 4; r++) oacc[dt][r] *= alpha;

        // B-frags of P^T: lane reads its own q-row, k-contiguous
        short8v bP[2];
#pragma unroll
        for (int c = 0; c < 2; c++)
            bP[c] = *(const short8v*)&Pt[wave][m][c * 32 + g * 8];

        // O^T[dt*16+g*4+r][q=m] += V^T · P^T
#pragma unroll
        for (int dt = 0; dt < 4; dt++) {
#pragma unroll
            for (int c = 0; c < 2; c++) {
                frag_u u;
                u.v4[0] = *(const short4v*)&Vt[dt * 16 + m][c * 32 + g * 8];
                u.v4[1] = *(const short4v*)&Vt[dt * 16 + m][c * 32 + g * 8 + 4];
                oacc[dt] = __builtin_amdgcn_mfma_f32_16x16x32_bf16(u.v8, bP[c], oacc[dt], 0, 0, 0);
            }
        }
    }

    // reduce l across quads (k-partitions)
    lrow += __shfl_xor(lrow, 16);
    lrow += __shfl_xor(lrow, 32);

    size_t zoff = (size_t)blockIdx.z * NUM_HEADS * BATCH + bh;
    size_t pbase = zoff * (SEQ_LEN * (size_t)HEAD_DIM);
    int q = q0w + m;
    bf16* orow = Op + pbase + (size_t)q * HEAD_DIM;
#pragma unroll
    for (int dt = 0; dt < 4; dt++) {
        short4v pk = {f2bs(oacc[dt][0]), f2bs(oacc[dt][1]), f2bs(oacc[dt][2]), f2bs(oacc[dt][3])};
        *(short4v*)&orow[dt * 16 + g * 4] = pk;
    }
    if (g == 0) mlout[zoff * SEQ_LEN + q] = make_float2(mrow, lrow);
}

// Merge 2 split partials -> attention output ab [TOKENS][D_MODEL]
__global__ void attn_merge(const bf16* __restrict__ Op, const float2* __restrict__ ml,
                           bf16* __restrict__ O) {
    int i = blockIdx.x * 256 + threadIdx.x;   // over 16*4096*64
    int d = i & 63;
    int q = (i >> 6) & (SEQ_LEN - 1);
    int bh = i >> 18;
    const int HQ = NUM_HEADS * BATCH * SEQ_LEN;
    float2 a = ml[bh * SEQ_LEN + q];
    float2 b = ml[HQ + bh * SEQ_LEN + q];
    float M = fmaxf(a.x, b.x);
    float w0 = __expf(a.x - M), w1 = __expf(b.x - M);
    float inv = 1.f / (a.y * w0 + b.y * w1);
    const size_t NP = (size_t)HQ * HEAD_DIM;
    float o = (b2f(Op[i]) * w0 + b2f(Op[NP + i]) * w1) * inv;
    O[((size_t)((bh >> 3) * SEQ_LEN + q)) * D_MODEL + (bh & 7) * HEAD_DIM + d] = f2b(o);
}

// ------------------------------------------------------------------------------
extern "C" void kernel_launch(void* const* d_in, const int* in_sizes, int n_in,
                              void* d_out, int out_size, void* d_ws, size_t ws_size,
                              hipStream_t stream) {
    const void* x     = d_in[0];
    const void* Wq    = d_in[1];
    const void* bq    = d_in[2];
    const void* Wk    = d_in[3];
    const void* bk    = d_in[4];
    const void* Wv    = d_in[5];
    const void* bv    = d_in[6];
    const void* Wo    = d_in[7];
    const void* bo    = d_in[8];
    const void* ln1_g = d_in[9];
    const void* ln1_b = d_in[10];
    const void* ln2_g = d_in[11];
    const void* ln2_b = d_in[12];
    const void* W1    = d_in[13];
    const void* b1    = d_in[14];
    const void* W2    = d_in[15];
    const void* b2    = d_in[16];

    // ---- workspace layout ----
    char* p = (char*)d_ws;
    int* flag = (int*)p;                      p += 256;
    size_t tok_d = (size_t)TOKENS * D_MODEL;
    char*  region2 = p;                       p += tok_d * 4 + tok_d * 2;  // 25.2 MB
    float* x1f  = (float*)region2;
    bf16*  hb   = (bf16*)(region2 + tok_d * 4);
    // split-K partials overlap region2 (x1f/hb dead during flash+merge):
    bf16*   Opart = (bf16*)region2;                                        // 16.78 MB
    float2* mlb   = (float2*)(region2 + (size_t)KSPLIT * NUM_HEADS * BATCH * SEQ_LEN * HEAD_DIM * 2);
    bf16*  bigA = (bf16*)p;                   p += (size_t)TOKENS * D_FF * 2;  // 33.6 MB
    bf16*  qkvb = bigA;                                   // [TOKENS][1536]
    bf16*  ab   = bigA + (size_t)TOKENS * QKV_STRIDE;     // [TOKENS][512]
    bf16*  ffb  = bigA;                                   // [TOKENS][2048]
    bf16*  Wqkvt = (bf16*)p;                  p += (size_t)QKV_STRIDE * D_MODEL * 2;
    bf16*  Wot   = (bf16*)p;                  p += (size_t)D_MODEL * D_MODEL * 2;
    bf16*  W1t   = (bf16*)p;                  p += (size_t)D_FF * D_MODEL * 2;
    bf16*  W2t   = (bf16*)p;                  p += (size_t)D_MODEL * D_FF * 2;
    bf16*  small = (bf16*)p;                  p += 6656 * 2;
    bf16* bias_qkv = small + 0;
    bf16* bias_o   = small + 1536;
    bf16* b1b      = small + 2048;
    bf16* b2b      = small + 4096;
    bf16* g1b      = small + 4608;
    bf16* be1b     = small + 5120;
    bf16* g2b      = small + 5632;
    bf16* be2b     = small + 6144;

    detect_kernel<<<1, 1024, 0, stream>>>((const unsigned int*)x, flag);

    cvt_transpose4<<<dim3(8, 8, 4), 256, 0, stream>>>(Wq, Wk, Wv, Wo, Wqkvt, flag);
    cvt_transpose<<<dim3(32, 8), 256, 0, stream>>>(W1, W1t, D_MODEL, D_FF, flag);
    cvt_transpose<<<dim3(8, 32), 256, 0, stream>>>(W2, W2t, D_FF, D_MODEL, flag);
    cvt_small<<<26, 256, 0, stream>>>(bq, bk, bv, bo, b1, b2, ln1_g, ln1_b, ln2_g, ln2_b,
                                      small, flag);

    // LN1 reads raw x (dtype per flag)
    ln_kernel<2><<<TOKENS, 256, 0, stream>>>(x, g1b, be1b, hb, flag);

    // fused QKV projection
    mfma_gemm<0, 0><<<dim3(QKV_STRIDE / 128, TOKENS / 128), 256, 0, stream>>>(
        hb, Wqkvt, bias_qkv, qkvb, flag, TOKENS, QKV_STRIDE, D_MODEL);

    flash_attn<<<dim3(64, 16, KSPLIT), 256, 0, stream>>>(qkvb, qkvb + 512, qkvb + 1024,
                                                         Opart, mlb);
    attn_merge<<<(NUM_HEADS * BATCH * SEQ_LEN * HEAD_DIM) / 256, 256, 0, stream>>>(
        Opart, mlb, ab);

    // O projection + residual(raw x) -> x1 (fp32); 512 blocks
    mfma_gemm64<3, 1><<<dim3(D_MODEL / 64, TOKENS / 128), 256, 0, stream>>>(
        ab, Wot, bias_o, nullptr, x, x1f, flag, TOKENS, D_MODEL, D_MODEL);

    ln_kernel<1><<<TOKENS, 256, 0, stream>>>(x1f, g2b, be2b, hb, flag);

    // FFN1 + GELU
    mfma_gemm<1, 0><<<dim3(D_FF / 128, TOKENS / 128), 256, 0, stream>>>(
        hb, W1t, b1b, ffb, flag, TOKENS, D_FF, D_MODEL);

    // FFN2 + residual(x1) -> out; 512 blocks
    mfma_gemm64<1, 2><<<dim3(D_MODEL / 64, TOKENS / 128), 256, 0, stream>>>(
        ffb, W2t, b2b, x1f, nullptr, d_out, flag, TOKENS, D_MODEL, D_FF);
}

// Round 7
// 404.212 us; speedup vs baseline: 28.6157x; 1.0641x over previous
//
#include <hip/hip_runtime.h>
#include <hip/hip_bf16.h>
#include <math.h>

typedef __hip_bfloat16 bf16;

#define D_MODEL 512
#define NUM_HEADS 8
#define HEAD_DIM 64
#define SEQ_LEN 4096
#define BATCH 2
#define D_FF 2048
#define TOKENS (BATCH * SEQ_LEN)
#define QKV_STRIDE 1536
#define KSPLIT 3

typedef short short4v __attribute__((ext_vector_type(4)));
typedef short short8v __attribute__((ext_vector_type(8)));
typedef float float4v __attribute__((ext_vector_type(4)));

union frag_u { short8v v8; short4v v4[2]; short s[8]; };
union pack_u { unsigned u[2]; short4v v4; };

__device__ __forceinline__ float b2f(bf16 v) { return __bfloat162float(v); }
__device__ __forceinline__ bf16 f2b(float v) { return __float2bfloat16(v); }
__device__ __forceinline__ short f2bs(float v) { bf16 t = __float2bfloat16(v); return *(short*)&t; }

// pack two f32 -> (bf16(hi)<<16)|bf16(lo) with round-to-nearest via +0x8000 + v_perm
__device__ __forceinline__ unsigned pack_bf16(float lo, float hi) {
    unsigned a = __float_as_uint(hi) + 0x8000u;
    unsigned b = __float_as_uint(lo) + 0x8000u;
    return __builtin_amdgcn_perm(a, b, 0x07060302u);
}

#define AS1(p) ((__attribute__((address_space(1))) void*)(p))
#define AS3(p) ((__attribute__((address_space(3))) void*)(p))

// ---------------------------------------------------------------------------
// Input dtype detection. flag=1 -> fp32 inputs, flag=0 -> bf16 inputs.
__global__ void detect_kernel(const unsigned int* __restrict__ x, int* __restrict__ flag) {
    __shared__ int cnt;
    if (threadIdx.x == 0) cnt = 0;
    __syncthreads();
    unsigned int w = x[threadIdx.x];
    unsigned int e = (w >> 7) & 0xFFu;
    if (e >= 110 && e <= 140) atomicAdd(&cnt, 1);
    __syncthreads();
    if (threadIdx.x == 0) flag[0] = (cnt >= (int)(blockDim.x / 2)) ? 0 : 1;
}

// ---------------- fused weight prep (transposes + small vectors) --------------
__device__ __forceinline__ void do_tr(const void* __restrict__ src, bf16* __restrict__ dst,
                                      int K, int N, int n0, int k0, int fl, int tid,
                                      bf16 (*tile)[65]) {
    int c = tid & 63, r4 = tid >> 6;
#pragma unroll
    for (int t = 0; t < 16; t++) {
        int r = t * 4 + r4;
        size_t si = (size_t)(k0 + r) * N + n0 + c;
        float v = fl ? ((const float*)src)[si] : b2f(((const bf16*)src)[si]);
        tile[r][c] = f2b(v);
    }
    __syncthreads();
#pragma unroll
    for (int t = 0; t < 16; t++) {
        int r = t * 4 + r4;
        dst[(size_t)(n0 + r) * K + k0 + c] = tile[c][r];
    }
}

__global__ void prep_kernel(const void* Wq, const void* Wk, const void* Wv, const void* Wo,
                            const void* W1, const void* W2,
                            const void* bq, const void* bk, const void* bv, const void* bo,
                            const void* b1, const void* b2,
                            const void* g1, const void* e1, const void* g2, const void* e2,
                            bf16* __restrict__ Wqkvt /* + Wot contiguous */,
                            bf16* __restrict__ W1t, bf16* __restrict__ W2t,
                            bf16* __restrict__ small, const int* __restrict__ flag) {
    __shared__ bf16 tile[64][65];
    int blk = blockIdx.x, tid = threadIdx.x;
    int fl = *flag;
    if (blk < 256) {                       // Wq|Wk|Wv|Wo 512x512
        int z = blk >> 6, tt = blk & 63;
        const void* src = (z == 0) ? Wq : (z == 1) ? Wk : (z == 2) ? Wv : Wo;
        do_tr(src, Wqkvt + (size_t)z * 512 * 512, 512, 512, (tt & 7) * 64, (tt >> 3) * 64,
              fl, tid, tile);
    } else if (blk < 512) {                // W1: [512][2048] -> [2048][512]
        int tt = blk - 256;
        do_tr(W1, W1t, 512, 2048, (tt & 31) * 64, (tt >> 5) * 64, fl, tid, tile);
    } else if (blk < 768) {                // W2: [2048][512] -> [512][2048]
        int tt = blk - 512;
        do_tr(W2, W2t, 2048, 512, (tt & 7) * 64, (tt >> 3) * 64, fl, tid, tile);
    } else {                               // small vectors
        int i = (blk - 768) * 256 + tid;   // 0..6655
        const void* src; int off;
        if (i < 512)       { src = bq; off = 0; }
        else if (i < 1024) { src = bk; off = 512; }
        else if (i < 1536) { src = bv; off = 1024; }
        else if (i < 2048) { src = bo; off = 1536; }
        else if (i < 4096) { src = b1; off = 2048; }
        else if (i < 4608) { src = b2; off = 4096; }
        else if (i < 5120) { src = g1; off = 4608; }
        else if (i < 5632) { src = e1; off = 5120; }
        else if (i < 6144) { src = g2; off = 5632; }
        else               { src = e2; off = 6144; }
        int j = i - off;
        small[i] = fl ? f2b(((const float*)src)[j]) : ((const bf16*)src)[j];
    }
}

// ---------------- LayerNorm: one block per token ------------------------------
// MODE: 0 = bf16 input, 2 = flag-chosen raw input.
template <int MODE>
__global__ void ln_kernel(const void* __restrict__ xv, const bf16* __restrict__ g,
                          const bf16* __restrict__ b, bf16* __restrict__ out,
                          const int* __restrict__ flag) {
    int t = blockIdx.x;
    int tid = threadIdx.x;
    int fl = (MODE == 2) ? *flag : 0;
    float v0, v1;
    if (fl) {
        const float* xr = (const float*)xv + (size_t)t * D_MODEL;
        v0 = xr[tid]; v1 = xr[tid + 256];
    } else {
        const bf16* xr = (const bf16*)xv + (size_t)t * D_MODEL;
        v0 = b2f(xr[tid]); v1 = b2f(xr[tid + 256]);
    }
    float s = v0 + v1, ss = v0 * v0 + v1 * v1;
    for (int o = 32; o > 0; o >>= 1) {
        s += __shfl_down(s, o);
        ss += __shfl_down(ss, o);
    }
    __shared__ float rs[4], rss[4], stat[2];
    int w = tid >> 6, l = tid & 63;
    if (l == 0) { rs[w] = s; rss[w] = ss; }
    __syncthreads();
    if (tid == 0) {
        float S = rs[0] + rs[1] + rs[2] + rs[3];
        float SS = rss[0] + rss[1] + rss[2] + rss[3];
        float mu = S / (float)D_MODEL;
        float var = SS / (float)D_MODEL - mu * mu;
        stat[0] = mu;
        stat[1] = rsqrtf(var + 1e-5f);
    }
    __syncthreads();
    float mu = stat[0], rstd = stat[1];
    bf16* orow = out + (size_t)t * D_MODEL;
    orow[tid]       = f2b((v0 - mu) * rstd * b2f(g[tid])       + b2f(b[tid]));
    orow[tid + 256] = f2b((v1 - mu) * rstd * b2f(g[tid + 256]) + b2f(b[tid + 256]));
}

__device__ __forceinline__ float gelu_tanh(float v) {
    float u = 0.7978845608f * (v + 0.044715f * v * v * v);
    float e2 = __expf(-2.f * u);
    return v / (1.f + e2);
}

// ---------------- MFMA GEMM 128x128 (m97 structure) ---------------------------
// ACT: 0 none, 1 tanh-GELU. Output bf16.
template <int ACT>
__global__ __launch_bounds__(256) void mfma_gemm(
    const bf16* __restrict__ A, const bf16* __restrict__ Wt,
    const bf16* __restrict__ bias, bf16* __restrict__ Cout,
    int M, int N, int K) {
    __shared__ bf16 As[128 * 64];
    __shared__ bf16 Bs[128 * 64];
    int tid = threadIdx.x, wave = tid >> 6, lane = tid & 63;
    int m = lane & 15, g = lane >> 4;
    int row0 = blockIdx.y * 128, col0 = blockIdx.x * 128;
    int R0 = (wave >> 1) * 64, C0 = (wave & 1) * 64;
    float4v acc[4][4] = {};

    int srow = lane >> 3;
    int scol = (lane & 7) * 8;
    const bf16* Ab = A  + (size_t)(row0 + wave * 8 + srow) * K + scol;
    const bf16* Bb = Wt + (size_t)(col0 + wave * 8 + srow) * K + scol;

    for (int k0 = 0; k0 < K; k0 += 64) {
#pragma unroll
        for (int t = 0; t < 4; t++) {
            int rbase = t * 32 + wave * 8;
            __builtin_amdgcn_global_load_lds(AS1(Ab + (size_t)(t * 32) * K + k0),
                                             AS3(&As[rbase * 64]), 16, 0, 0);
            __builtin_amdgcn_global_load_lds(AS1(Bb + (size_t)(t * 32) * K + k0),
                                             AS3(&Bs[rbase * 64]), 16, 0, 0);
        }
        __syncthreads();
#pragma unroll
        for (int kk = 0; kk < 2; kk++) {
            short8v fa[4], fb[4];
#pragma unroll
            for (int i = 0; i < 4; i++)
                fa[i] = *(const short8v*)&As[(R0 + i * 16 + m) * 64 + kk * 32 + g * 8];
#pragma unroll
            for (int j = 0; j < 4; j++)
                fb[j] = *(const short8v*)&Bs[(C0 + j * 16 + m) * 64 + kk * 32 + g * 8];
#pragma unroll
            for (int i = 0; i < 4; i++)
#pragma unroll
                for (int j = 0; j < 4; j++)
                    acc[i][j] = __builtin_amdgcn_mfma_f32_16x16x32_bf16(fa[i], fb[j], acc[i][j], 0, 0, 0);
        }
        __syncthreads();
    }

#pragma unroll
    for (int i = 0; i < 4; i++) {
#pragma unroll
        for (int r = 0; r < 4; r++) {
            int row = row0 + R0 + i * 16 + g * 4 + r;
#pragma unroll
            for (int j = 0; j < 4; j++) {
                int col = col0 + C0 + j * 16 + m;
                float v = acc[i][j][r] + b2f(bias[col]);
                if (ACT == 1) v = gelu_tanh(v);
                Cout[(size_t)row * N + col] = f2b(v);
            }
        }
    }
}

// ---------------- MFMA GEMM 128x64 tile (N=512 GEMMs: 512 blocks) -------------
// RES: 2 bf16 res, 3 raw-input res (dtype per flag). OUTMODE: 0 bf16, 2 flag.
template <int RES, int OUTMODE>
__global__ __launch_bounds__(256) void mfma_gemm64(
    const bf16* __restrict__ A, const bf16* __restrict__ Wt,
    const bf16* __restrict__ bias, const void* __restrict__ res,
    void* __restrict__ Cout, const int* __restrict__ flag, int M, int N, int K) {
    __shared__ bf16 As[128 * 64];
    __shared__ bf16 Bs[64 * 64];
    int tid = threadIdx.x, wave = tid >> 6, lane = tid & 63;
    int m = lane & 15, g = lane >> 4;
    int row0 = blockIdx.y * 128, col0 = blockIdx.x * 64;
    int R0 = wave * 32;
    int fl = (OUTMODE == 2 || RES == 3) ? *flag : 0;
    float4v acc[2][4] = {};

    int srow = lane >> 3;
    int scol = (lane & 7) * 8;
    const bf16* Ab = A  + (size_t)(row0 + wave * 8 + srow) * K + scol;
    const bf16* Bb = Wt + (size_t)(col0 + wave * 8 + srow) * K + scol;

    for (int k0 = 0; k0 < K; k0 += 64) {
#pragma unroll
        for (int t = 0; t < 4; t++) {
            __builtin_amdgcn_global_load_lds(AS1(Ab + (size_t)(t * 32) * K + k0),
                                             AS3(&As[(t * 32 + wave * 8) * 64]), 16, 0, 0);
            if (t < 2)
                __builtin_amdgcn_global_load_lds(AS1(Bb + (size_t)(t * 32) * K + k0),
                                                 AS3(&Bs[(t * 32 + wave * 8) * 64]), 16, 0, 0);
        }
        __syncthreads();
#pragma unroll
        for (int kk = 0; kk < 2; kk++) {
            short8v fa[2], fb[4];
#pragma unroll
            for (int i = 0; i < 2; i++)
                fa[i] = *(const short8v*)&As[(R0 + i * 16 + m) * 64 + kk * 32 + g * 8];
#pragma unroll
            for (int j = 0; j < 4; j++)
                fb[j] = *(const short8v*)&Bs[(j * 16 + m) * 64 + kk * 32 + g * 8];
#pragma unroll
            for (int i = 0; i < 2; i++)
#pragma unroll
                for (int j = 0; j < 4; j++)
                    acc[i][j] = __builtin_amdgcn_mfma_f32_16x16x32_bf16(fa[i], fb[j], acc[i][j], 0, 0, 0);
        }
        __syncthreads();
    }

#pragma unroll
    for (int i = 0; i < 2; i++) {
#pragma unroll
        for (int r = 0; r < 4; r++) {
            int row = row0 + R0 + i * 16 + g * 4 + r;
#pragma unroll
            for (int j = 0; j < 4; j++) {
                int col = col0 + j * 16 + m;
                float v = acc[i][j][r] + b2f(bias[col]);
                size_t idx = (size_t)row * N + col;
                if (RES == 2) v += b2f(((const bf16*)res)[idx]);
                if (RES == 3) v += fl ? ((const float*)res)[idx]
                                      : b2f(((const bf16*)res)[idx]);
                if (OUTMODE == 0) ((bf16*)Cout)[idx] = f2b(v);
                else {
                    if (fl) ((float*)Cout)[idx] = v;
                    else ((bf16*)Cout)[idx] = f2b(v);
                }
            }
        }
    }
}

// ---------------- V transpose: qkvb V-part -> Vt_g [bh][dim][seq] -------------
__global__ void v_transpose(const bf16* __restrict__ qkv, bf16* __restrict__ Vt_g) {
    __shared__ bf16 tile[64][65];
    int s0 = blockIdx.x * 64;
    int bh = blockIdx.y;
    int b = bh >> 3, h = bh & 7;
    int c = threadIdx.x & 63, r4 = threadIdx.x >> 6;
    const bf16* src = qkv + ((size_t)b * SEQ_LEN + s0) * QKV_STRIDE + 1024 + h * 64;
#pragma unroll
    for (int t = 0; t < 16; t++) {
        int r = t * 4 + r4;                       // r = token, c = dim
        tile[r][c] = src[(size_t)r * QKV_STRIDE + c];
    }
    __syncthreads();
    bf16* dst = Vt_g + (size_t)bh * 64 * SEQ_LEN + s0;
#pragma unroll
    for (int t = 0; t < 16; t++) {
        int r = t * 4 + r4;                       // r = dim, c = token
        dst[(size_t)r * SEQ_LEN + c] = tile[c][r];
    }
}

// ---------------- Flash attention, S^T formulation, split-K=3 -----------------
__global__ __launch_bounds__(256) void flash_attn(const bf16* __restrict__ Q,
                                                  const bf16* __restrict__ K,
                                                  const bf16* __restrict__ Vt_g,
                                                  bf16* __restrict__ Op,
                                                  float2* __restrict__ mlout) {
    __shared__ bf16 Ks[64][72];
    __shared__ bf16 Vt[64][68];
    __shared__ bf16 Pt[4][16][72];   // per-wave P^T [q=m][k]

    int tid = threadIdx.x;
    int wave = tid >> 6, lane = tid & 63;
    int m = lane & 15, g = lane >> 4;

    int bh = blockIdx.y;
    size_t base = (size_t)(bh >> 3) * SEQ_LEN * QKV_STRIDE + (size_t)(bh & 7) * HEAD_DIM;
    int q0w = blockIdx.x * 64 + wave * 16;

    short8v aQ[2];
    {
        const bf16* qp = Q + base + (size_t)(q0w + m) * QKV_STRIDE + g * 8;
#pragma unroll
        for (int c = 0; c < 2; c++) {
            frag_u u;
#pragma unroll
            for (int j = 0; j < 8; j++) u.s[j] = f2bs(b2f(qp[c * 32 + j]) * 0.125f);
            aQ[c] = u.v8;
        }
    }

    float mrow = -1e30f, lrow = 0.f;
    float4v oacc[4] = {};

    int sk = tid >> 2;
    int sd = (tid & 3) * 16;
    int vrow = tid >> 2;             // dim
    int vcol = (tid & 3) * 16;       // key offset

    const unsigned short* Ku = (const unsigned short*)(K + base);
    const unsigned short* Vg = (const unsigned short*)Vt_g +
                               (size_t)bh * 64 * SEQ_LEN + (size_t)vrow * SEQ_LEN;

    int t0 = (blockIdx.z * 64) / KSPLIT;
    int t1 = ((blockIdx.z + 1) * 64) / KSPLIT;
    for (int t = t0; t < t1; t++) {
        int kt0 = t * 64;
        __syncthreads();
        {   // K stage (row-major)
            const unsigned short* kp = Ku + (size_t)(kt0 + sk) * QKV_STRIDE + sd;
            *(short8v*)&Ks[sk][sd]     = *(const short8v*)(kp);
            *(short8v*)&Ks[sk][sd + 8] = *(const short8v*)(kp + 8);
        }
        {   // V stage from global V^T: vector loads, no transpose work
            frag_u u0, u1;
            u0.v8 = *(const short8v*)(Vg + kt0 + vcol);
            u1.v8 = *(const short8v*)(Vg + kt0 + vcol + 8);
            *(short4v*)&Vt[vrow][vcol]      = u0.v4[0];
            *(short4v*)&Vt[vrow][vcol + 4]  = u0.v4[1];
            *(short4v*)&Vt[vrow][vcol + 8]  = u1.v4[0];
            *(short4v*)&Vt[vrow][vcol + 12] = u1.v4[1];
        }
        __syncthreads();

        float4v st[4];
#pragma unroll
        for (int kt = 0; kt < 4; kt++) {
            short8v bK0 = *(const short8v*)&Ks[kt * 16 + m][g * 8];
            short8v bK1 = *(const short8v*)&Ks[kt * 16 + m][32 + g * 8];
            float4v a = {0.f, 0.f, 0.f, 0.f};
            a = __builtin_amdgcn_mfma_f32_16x16x32_bf16(bK0, aQ[0], a, 0, 0, 0);
            a = __builtin_amdgcn_mfma_f32_16x16x32_bf16(bK1, aQ[1], a, 0, 0, 0);
            st[kt] = a;
        }

        float tm = st[0][0];
#pragma unroll
        for (int kt = 0; kt < 4; kt++)
#pragma unroll
            for (int r = 0; r < 4; r++) tm = fmaxf(tm, st[kt][r]);
        tm = fmaxf(tm, __shfl_xor(tm, 16));
        tm = fmaxf(tm, __shfl_xor(tm, 32));
        float mnew = fmaxf(mrow, tm);
        float alpha = __expf(mrow - mnew);
        mrow = mnew;

        float psum = 0.f;
#pragma unroll
        for (int kt = 0; kt < 4; kt++) {
            float p0 = __expf(st[kt][0] - mnew);
            float p1 = __expf(st[kt][1] - mnew);
            float p2 = __expf(st[kt][2] - mnew);
            float p3 = __expf(st[kt][3] - mnew);
            psum += (p0 + p1) + (p2 + p3);
            pack_u pp;
            pp.u[0] = pack_bf16(p0, p1);
            pp.u[1] = pack_bf16(p2, p3);
            *(short4v*)&Pt[wave][m][kt * 16 + g * 4] = pp.v4;
        }
        lrow = lrow * alpha + psum;
#pragma unroll
        for (int dt = 0; dt < 4; dt++)
#pragma unroll
            for (int r = 0; r < 4; r++) oacc[dt][r] *= alpha;

        short8v bP[2];
#pragma unroll
        for (int c = 0; c < 2; c++)
            bP[c] = *(const short8v*)&Pt[wave][m][c * 32 + g * 8];

#pragma unroll
        for (int dt = 0; dt < 4; dt++) {
#pragma unroll
            for (int c = 0; c < 2; c++) {
                frag_u u;
                u.v4[0] = *(const short4v*)&Vt[dt * 16 + m][c * 32 + g * 8];
                u.v4[1] = *(const short4v*)&Vt[dt * 16 + m][c * 32 + g * 8 + 4];
                oacc[dt] = __builtin_amdgcn_mfma_f32_16x16x32_bf16(u.v8, bP[c], oacc[dt], 0, 0, 0);
            }
        }
    }

    lrow += __shfl_xor(lrow, 16);
    lrow += __shfl_xor(lrow, 32);

    size_t zoff = (size_t)blockIdx.z * NUM_HEADS * BATCH + bh;
    size_t pbase = zoff * (SEQ_LEN * (size_t)HEAD_DIM);
    int q = q0w + m;
    bf16* orow = Op + pbase + (size_t)q * HEAD_DIM;
#pragma unroll
    for (int dt = 0; dt < 4; dt++) {
        pack_u oo;
        oo.u[0] = pack_bf16(oacc[dt][0], oacc[dt][1]);
        oo.u[1] = pack_bf16(oacc[dt][2], oacc[dt][3]);
        *(short4v*)&orow[dt * 16 + g * 4] = oo.v4;
    }
    if (g == 0) mlout[zoff * SEQ_LEN + q] = make_float2(mrow, lrow);
}

// Merge KSPLIT partials -> attention output ab [TOKENS][D_MODEL]
__global__ void attn_merge(const bf16* __restrict__ Op, const float2* __restrict__ ml,
                           bf16* __restrict__ O) {
    int i = blockIdx.x * 256 + threadIdx.x;   // over 16*4096*64
    int d = i & 63;
    int q = (i >> 6) & (SEQ_LEN - 1);
    int bh = i >> 18;
    const int HQ = NUM_HEADS * BATCH * SEQ_LEN;
    float2 a0 = ml[bh * SEQ_LEN + q];
    float2 a1 = ml[HQ + bh * SEQ_LEN + q];
    float2 a2 = ml[2 * HQ + bh * SEQ_LEN + q];
    float M = fmaxf(a0.x, fmaxf(a1.x, a2.x));
    float w0 = __expf(a0.x - M), w1 = __expf(a1.x - M), w2 = __expf(a2.x - M);
    float inv = 1.f / (a0.y * w0 + a1.y * w1 + a2.y * w2);
    const size_t NP = (size_t)HQ * HEAD_DIM;
    float o = (b2f(Op[i]) * w0 + b2f(Op[NP + i]) * w1 + b2f(Op[2 * NP + i]) * w2) * inv;
    O[((size_t)((bh >> 3) * SEQ_LEN + q)) * D_MODEL + (bh & 7) * HEAD_DIM + d] = f2b(o);
}

// ------------------------------------------------------------------------------
extern "C" void kernel_launch(void* const* d_in, const int* in_sizes, int n_in,
                              void* d_out, int out_size, void* d_ws, size_t ws_size,
                              hipStream_t stream) {
    const void* x     = d_in[0];
    const void* Wq    = d_in[1];
    const void* bq    = d_in[2];
    const void* Wk    = d_in[3];
    const void* bk    = d_in[4];
    const void* Wv    = d_in[5];
    const void* bv    = d_in[6];
    const void* Wo    = d_in[7];
    const void* bo    = d_in[8];
    const void* ln1_g = d_in[9];
    const void* ln1_b = d_in[10];
    const void* ln2_g = d_in[11];
    const void* ln2_b = d_in[12];
    const void* W1    = d_in[13];
    const void* b1    = d_in[14];
    const void* W2    = d_in[15];
    const void* b2    = d_in[16];

    // ---- workspace layout ----
    char* p = (char*)d_ws;
    int* flag = (int*)p;                      p += 256;
    size_t tok_d = (size_t)TOKENS * D_MODEL;
    // region2: KSPLIT bf16 O-partials (25.2 MB) overlay x1b+hb
    char* region2 = p;                        p += (size_t)KSPLIT * NUM_HEADS * BATCH * SEQ_LEN * HEAD_DIM * 2;
    bf16* x1b   = (bf16*)region2;                              // [TOKENS][512]
    bf16* hb    = (bf16*)(region2 + tok_d * 2);                // [TOKENS][512]
    bf16* Opart = (bf16*)region2;
    bf16*  bigA = (bf16*)p;                   p += (size_t)TOKENS * D_FF * 2;  // 33.6 MB
    bf16*  qkvb = bigA;                                   // [TOKENS][1536]
    bf16*  ab   = bigA + (size_t)TOKENS * QKV_STRIDE;     // [TOKENS][512]
    bf16*  ffb  = bigA;                                   // [TOKENS][2048]
    bf16*  Wqkvt = (bf16*)p;                  p += (size_t)QKV_STRIDE * D_MODEL * 2;
    bf16*  Wot   = (bf16*)p;                  p += (size_t)D_MODEL * D_MODEL * 2;  // contiguous
    bf16*  W1t   = (bf16*)p;                  p += (size_t)D_FF * D_MODEL * 2;
    bf16*  W2t   = (bf16*)p;                  p += (size_t)D_MODEL * D_FF * 2;
    bf16*  Vtg   = (bf16*)p;                  p += (size_t)NUM_HEADS * BATCH * HEAD_DIM * SEQ_LEN * 2;
    float2* mlb  = (float2*)p;                p += (size_t)KSPLIT * NUM_HEADS * BATCH * SEQ_LEN * sizeof(float2);
    bf16*  small = (bf16*)p;                  p += 6656 * 2;
    bf16* bias_qkv = small + 0;
    bf16* bias_o   = small + 1536;
    bf16* b1b      = small + 2048;
    bf16* b2b      = small + 4096;
    bf16* g1b      = small + 4608;
    bf16* be1b     = small + 5120;
    bf16* g2b      = small + 5632;
    bf16* be2b     = small + 6144;

    detect_kernel<<<1, 1024, 0, stream>>>((const unsigned int*)x, flag);

    prep_kernel<<<794, 256, 0, stream>>>(Wq, Wk, Wv, Wo, W1, W2,
                                         bq, bk, bv, bo, b1, b2,
                                         ln1_g, ln1_b, ln2_g, ln2_b,
                                         Wqkvt, W1t, W2t, small, flag);

    // LN1 reads raw x (dtype per flag)
    ln_kernel<2><<<TOKENS, 256, 0, stream>>>(x, g1b, be1b, hb, flag);

    // fused QKV projection
    mfma_gemm<0><<<dim3(QKV_STRIDE / 128, TOKENS / 128), 256, 0, stream>>>(
        hb, Wqkvt, bias_qkv, qkvb, TOKENS, QKV_STRIDE, D_MODEL);

    // V -> global V^T [bh][dim][seq]
    v_transpose<<<dim3(SEQ_LEN / 64, NUM_HEADS * BATCH), 256, 0, stream>>>(qkvb, Vtg);

    flash_attn<<<dim3(64, 16, KSPLIT), 256, 0, stream>>>(qkvb, qkvb + 512, Vtg,
                                                         Opart, mlb);
    attn_merge<<<(NUM_HEADS * BATCH * SEQ_LEN * HEAD_DIM) / 256, 256, 0, stream>>>(
        Opart, mlb, ab);

    // O projection + residual(raw x) -> x1 (bf16); 512 blocks
    mfma_gemm64<3, 0><<<dim3(D_MODEL / 64, TOKENS / 128), 256, 0, stream>>>(
        ab, Wot, bias_o, x, x1b, flag, TOKENS, D_MODEL, D_MODEL);

    ln_kernel<0><<<TOKENS, 256, 0, stream>>>(x1b, g2b, be2b, hb, flag);

    // FFN1 + GELU
    mfma_gemm<1><<<dim3(D_FF / 128, TOKENS / 128), 256, 0, stream>>>(
        hb, W1t, b1b, ffb, TOKENS, D_FF, D_MODEL);

    // FFN2 + residual(x1 bf16) -> out (dtype per flag); 512 blocks
    mfma_gemm64<2, 2><<<dim3(D_MODEL / 64, TOKENS / 128), 256, 0, stream>>>(
        ffb, W2t, b2b, x1b, d_out, flag, TOKENS, D_MODEL, D_FF);
}

// Round 8
// 369.709 us; speedup vs baseline: 31.2863x; 1.0933x over previous
//
#include <hip/hip_runtime.h>
#include <hip/hip_bf16.h>
#include <math.h>

typedef __hip_bfloat16 bf16;

#define D_MODEL 512
#define NUM_HEADS 8
#define HEAD_DIM 64
#define SEQ_LEN 4096
#define BATCH 2
#define D_FF 2048
#define TOKENS (BATCH * SEQ_LEN)
#define QKV_STRIDE 1536
#define KSPLIT 2

typedef short short4v __attribute__((ext_vector_type(4)));
typedef short short8v __attribute__((ext_vector_type(8)));
typedef float float4v __attribute__((ext_vector_type(4)));

union frag_u { short8v v8; short4v v4[2]; short s[8]; };
union pack_u { unsigned u[2]; short4v v4; };

__device__ __forceinline__ float b2f(bf16 v) { return __bfloat162float(v); }
__device__ __forceinline__ bf16 f2b(float v) { return __float2bfloat16(v); }
__device__ __forceinline__ short f2bs(float v) { bf16 t = __float2bfloat16(v); return *(short*)&t; }
__device__ __forceinline__ float exp2fast(float x) { return __builtin_amdgcn_exp2f(x); }

// pack two f32 -> (bf16(hi)<<16)|bf16(lo), round-to-nearest via +0x8000 + v_perm
__device__ __forceinline__ unsigned pack_bf16(float lo, float hi) {
    unsigned a = __float_as_uint(hi) + 0x8000u;
    unsigned b = __float_as_uint(lo) + 0x8000u;
    return __builtin_amdgcn_perm(a, b, 0x07060302u);
}

#define AS1(p) ((__attribute__((address_space(1))) void*)(p))
#define AS3(p) ((__attribute__((address_space(3))) void*)(p))

// Self-detection: 1 if fp32 inputs, 0 if bf16. All lanes sample words 0..63 of x
// (identical ballot in every wave -> deterministic, no sync needed).
__device__ __forceinline__ int self_detect(const unsigned* __restrict__ xw, int tid) {
    unsigned w = xw[tid & 63];
    unsigned e = (w >> 7) & 0xFFu;
    unsigned long long b = __ballot(e >= 110 && e <= 140);
    return __popcll(b) < 32;
}

// ---------------- fused weight prep (transposes + small vectors + flag) -------
__device__ __forceinline__ void do_tr(const void* __restrict__ src, bf16* __restrict__ dst,
                                      int K, int N, int n0, int k0, int fl, int tid,
                                      bf16 (*tile)[65]) {
    int c = tid & 63, r4 = tid >> 6;
#pragma unroll
    for (int t = 0; t < 16; t++) {
        int r = t * 4 + r4;
        size_t si = (size_t)(k0 + r) * N + n0 + c;
        float v = fl ? ((const float*)src)[si] : b2f(((const bf16*)src)[si]);
        tile[r][c] = f2b(v);
    }
    __syncthreads();
#pragma unroll
    for (int t = 0; t < 16; t++) {
        int r = t * 4 + r4;
        dst[(size_t)(n0 + r) * K + k0 + c] = tile[c][r];
    }
}

__global__ void prep_kernel(const void* x, const void* Wq, const void* Wk, const void* Wv,
                            const void* Wo, const void* W1, const void* W2,
                            const void* bq, const void* bk, const void* bv, const void* bo,
                            const void* b1, const void* b2,
                            const void* g1, const void* e1, const void* g2, const void* e2,
                            bf16* __restrict__ Wqkvt /* + Wot contiguous */,
                            bf16* __restrict__ W1t, bf16* __restrict__ W2t,
                            bf16* __restrict__ small, int* __restrict__ flag) {
    __shared__ bf16 tile[64][65];
    int blk = blockIdx.x, tid = threadIdx.x;
    int fl = self_detect((const unsigned*)x, tid);
    if (blk == 0 && tid == 0) flag[0] = fl;   // publish for downstream kernels
    if (blk < 256) {                       // Wq|Wk|Wv|Wo 512x512
        int z = blk >> 6, tt = blk & 63;
        const void* src = (z == 0) ? Wq : (z == 1) ? Wk : (z == 2) ? Wv : Wo;
        do_tr(src, Wqkvt + (size_t)z * 512 * 512, 512, 512, (tt & 7) * 64, (tt >> 3) * 64,
              fl, tid, tile);
    } else if (blk < 512) {                // W1: [512][2048] -> [2048][512]
        int tt = blk - 256;
        do_tr(W1, W1t, 512, 2048, (tt & 31) * 64, (tt >> 5) * 64, fl, tid, tile);
    } else if (blk < 768) {                // W2: [2048][512] -> [512][2048]
        int tt = blk - 512;
        do_tr(W2, W2t, 2048, 512, (tt & 7) * 64, (tt >> 3) * 64, fl, tid, tile);
    } else {                               // small vectors
        int i = (blk - 768) * 256 + tid;   // 0..6655
        const void* src; int off;
        if (i < 512)       { src = bq; off = 0; }
        else if (i < 1024) { src = bk; off = 512; }
        else if (i < 1536) { src = bv; off = 1024; }
        else if (i < 2048) { src = bo; off = 1536; }
        else if (i < 4096) { src = b1; off = 2048; }
        else if (i < 4608) { src = b2; off = 4096; }
        else if (i < 5120) { src = g1; off = 4608; }
        else if (i < 5632) { src = e1; off = 5120; }
        else if (i < 6144) { src = g2; off = 5632; }
        else               { src = e2; off = 6144; }
        int j = i - off;
        small[i] = fl ? f2b(((const float*)src)[j]) : ((const bf16*)src)[j];
    }
}

// ---------------- LayerNorm: one block per token ------------------------------
// MODE: 0 = bf16 input, 2 = flag-chosen raw input.
template <int MODE>
__global__ void ln_kernel(const void* __restrict__ xv, const bf16* __restrict__ g,
                          const bf16* __restrict__ b, bf16* __restrict__ out,
                          const int* __restrict__ flag) {
    int t = blockIdx.x;
    int tid = threadIdx.x;
    int fl = (MODE == 2) ? *flag : 0;
    float v0, v1;
    if (fl) {
        const float* xr = (const float*)xv + (size_t)t * D_MODEL;
        v0 = xr[tid]; v1 = xr[tid + 256];
    } else {
        const bf16* xr = (const bf16*)xv + (size_t)t * D_MODEL;
        v0 = b2f(xr[tid]); v1 = b2f(xr[tid + 256]);
    }
    float s = v0 + v1, ss = v0 * v0 + v1 * v1;
    for (int o = 32; o > 0; o >>= 1) {
        s += __shfl_down(s, o);
        ss += __shfl_down(ss, o);
    }
    __shared__ float rs[4], rss[4], stat[2];
    int w = tid >> 6, l = tid & 63;
    if (l == 0) { rs[w] = s; rss[w] = ss; }
    __syncthreads();
    if (tid == 0) {
        float S = rs[0] + rs[1] + rs[2] + rs[3];
        float SS = rss[0] + rss[1] + rss[2] + rss[3];
        float mu = S / (float)D_MODEL;
        float var = SS / (float)D_MODEL - mu * mu;
        stat[0] = mu;
        stat[1] = rsqrtf(var + 1e-5f);
    }
    __syncthreads();
    float mu = stat[0], rstd = stat[1];
    bf16* orow = out + (size_t)t * D_MODEL;
    orow[tid]       = f2b((v0 - mu) * rstd * b2f(g[tid])       + b2f(b[tid]));
    orow[tid + 256] = f2b((v1 - mu) * rstd * b2f(g[tid + 256]) + b2f(b[tid + 256]));
}

__device__ __forceinline__ float gelu_tanh(float v) {
    float u = 0.7978845608f * (v + 0.044715f * v * v * v);
    float e2 = __expf(-2.f * u);
    return v / (1.f + e2);
}

// ---------------- MFMA GEMM 128x128 (m97 structure) ---------------------------
template <int ACT>
__global__ __launch_bounds__(256) void mfma_gemm(
    const bf16* __restrict__ A, const bf16* __restrict__ Wt,
    const bf16* __restrict__ bias, bf16* __restrict__ Cout,
    int M, int N, int K) {
    __shared__ bf16 As[128 * 64];
    __shared__ bf16 Bs[128 * 64];
    int tid = threadIdx.x, wave = tid >> 6, lane = tid & 63;
    int m = lane & 15, g = lane >> 4;
    int row0 = blockIdx.y * 128, col0 = blockIdx.x * 128;
    int R0 = (wave >> 1) * 64, C0 = (wave & 1) * 64;
    float4v acc[4][4] = {};

    int srow = lane >> 3;
    int scol = (lane & 7) * 8;
    const bf16* Ab = A  + (size_t)(row0 + wave * 8 + srow) * K + scol;
    const bf16* Bb = Wt + (size_t)(col0 + wave * 8 + srow) * K + scol;

    for (int k0 = 0; k0 < K; k0 += 64) {
#pragma unroll
        for (int t = 0; t < 4; t++) {
            int rbase = t * 32 + wave * 8;
            __builtin_amdgcn_global_load_lds(AS1(Ab + (size_t)(t * 32) * K + k0),
                                             AS3(&As[rbase * 64]), 16, 0, 0);
            __builtin_amdgcn_global_load_lds(AS1(Bb + (size_t)(t * 32) * K + k0),
                                             AS3(&Bs[rbase * 64]), 16, 0, 0);
        }
        __syncthreads();
#pragma unroll
        for (int kk = 0; kk < 2; kk++) {
            short8v fa[4], fb[4];
#pragma unroll
            for (int i = 0; i < 4; i++)
                fa[i] = *(const short8v*)&As[(R0 + i * 16 + m) * 64 + kk * 32 + g * 8];
#pragma unroll
            for (int j = 0; j < 4; j++)
                fb[j] = *(const short8v*)&Bs[(C0 + j * 16 + m) * 64 + kk * 32 + g * 8];
#pragma unroll
            for (int i = 0; i < 4; i++)
#pragma unroll
                for (int j = 0; j < 4; j++)
                    acc[i][j] = __builtin_amdgcn_mfma_f32_16x16x32_bf16(fa[i], fb[j], acc[i][j], 0, 0, 0);
        }
        __syncthreads();
    }

#pragma unroll
    for (int i = 0; i < 4; i++) {
#pragma unroll
        for (int r = 0; r < 4; r++) {
            int row = row0 + R0 + i * 16 + g * 4 + r;
#pragma unroll
            for (int j = 0; j < 4; j++) {
                int col = col0 + C0 + j * 16 + m;
                float v = acc[i][j][r] + b2f(bias[col]);
                if (ACT == 1) v = gelu_tanh(v);
                Cout[(size_t)row * N + col] = f2b(v);
            }
        }
    }
}

// ---------------- MFMA GEMM 128x64 tile (N=512 GEMMs: 512 blocks) -------------
// RES: 2 bf16 res, 3 raw-input res (dtype per flag). OUTMODE: 0 bf16, 2 flag.
template <int RES, int OUTMODE>
__global__ __launch_bounds__(256) void mfma_gemm64(
    const bf16* __restrict__ A, const bf16* __restrict__ Wt,
    const bf16* __restrict__ bias, const void* __restrict__ res,
    void* __restrict__ Cout, const int* __restrict__ flag, int M, int N, int K) {
    __shared__ bf16 As[128 * 64];
    __shared__ bf16 Bs[64 * 64];
    int tid = threadIdx.x, wave = tid >> 6, lane = tid & 63;
    int m = lane & 15, g = lane >> 4;
    int row0 = blockIdx.y * 128, col0 = blockIdx.x * 64;
    int R0 = wave * 32;
    int fl = (OUTMODE == 2 || RES == 3) ? *flag : 0;
    float4v acc[2][4] = {};

    int srow = lane >> 3;
    int scol = (lane & 7) * 8;
    const bf16* Ab = A  + (size_t)(row0 + wave * 8 + srow) * K + scol;
    const bf16* Bb = Wt + (size_t)(col0 + wave * 8 + srow) * K + scol;

    for (int k0 = 0; k0 < K; k0 += 64) {
#pragma unroll
        for (int t = 0; t < 4; t++) {
            __builtin_amdgcn_global_load_lds(AS1(Ab + (size_t)(t * 32) * K + k0),
                                             AS3(&As[(t * 32 + wave * 8) * 64]), 16, 0, 0);
            if (t < 2)
                __builtin_amdgcn_global_load_lds(AS1(Bb + (size_t)(t * 32) * K + k0),
                                                 AS3(&Bs[(t * 32 + wave * 8) * 64]), 16, 0, 0);
        }
        __syncthreads();
#pragma unroll
        for (int kk = 0; kk < 2; kk++) {
            short8v fa[2], fb[4];
#pragma unroll
            for (int i = 0; i < 2; i++)
                fa[i] = *(const short8v*)&As[(R0 + i * 16 + m) * 64 + kk * 32 + g * 8];
#pragma unroll
            for (int j = 0; j < 4; j++)
                fb[j] = *(const short8v*)&Bs[(j * 16 + m) * 64 + kk * 32 + g * 8];
#pragma unroll
            for (int i = 0; i < 2; i++)
#pragma unroll
                for (int j = 0; j < 4; j++)
                    acc[i][j] = __builtin_amdgcn_mfma_f32_16x16x32_bf16(fa[i], fb[j], acc[i][j], 0, 0, 0);
        }
        __syncthreads();
    }

#pragma unroll
    for (int i = 0; i < 2; i++) {
#pragma unroll
        for (int r = 0; r < 4; r++) {
            int row = row0 + R0 + i * 16 + g * 4 + r;
#pragma unroll
            for (int j = 0; j < 4; j++) {
                int col = col0 + j * 16 + m;
                float v = acc[i][j][r] + b2f(bias[col]);
                size_t idx = (size_t)row * N + col;
                if (RES == 2) v += b2f(((const bf16*)res)[idx]);
                if (RES == 3) v += fl ? ((const float*)res)[idx]
                                      : b2f(((const bf16*)res)[idx]);
                if (OUTMODE == 0) ((bf16*)Cout)[idx] = f2b(v);
                else {
                    if (fl) ((float*)Cout)[idx] = v;
                    else ((bf16*)Cout)[idx] = f2b(v);
                }
            }
        }
    }
}

// ---------------- V transpose: qkvb V-part -> Vt_g [bh][dim][seq] -------------
__global__ void v_transpose(const bf16* __restrict__ qkv, bf16* __restrict__ Vt_g) {
    __shared__ bf16 tile[64][65];
    int s0 = blockIdx.x * 64;
    int bh = blockIdx.y;
    int b = bh >> 3, h = bh & 7;
    int c = threadIdx.x & 63, r4 = threadIdx.x >> 6;
    const bf16* src = qkv + ((size_t)b * SEQ_LEN + s0) * QKV_STRIDE + 1024 + h * 64;
#pragma unroll
    for (int t = 0; t < 16; t++) {
        int r = t * 4 + r4;
        tile[r][c] = src[(size_t)r * QKV_STRIDE + c];
    }
    __syncthreads();
    bf16* dst = Vt_g + (size_t)bh * 64 * SEQ_LEN + s0;
#pragma unroll
    for (int t = 0; t < 16; t++) {
        int r = t * 4 + r4;
        dst[(size_t)r * SEQ_LEN + c] = tile[c][r];
    }
}

// ---------------- Flash attention, S^T formulation, 32q/wave, split-K=2 -------
// Each wave owns 32 q-rows (2 m-tiles). MFMA A-operands (K, V^T) are shared
// across the 2 m-tiles -> Ks/Vt LDS reads amortized over 2x the work.
// exp2-domain softmax: Q pre-scaled by 0.125*log2(e).
__global__ __launch_bounds__(256, 4) void flash_attn(const bf16* __restrict__ Q,
                                                     const bf16* __restrict__ K,
                                                     const bf16* __restrict__ Vt_g,
                                                     bf16* __restrict__ Op,
                                                     float2* __restrict__ mlout) {
    __shared__ bf16 Ks[64][72];
    __shared__ bf16 Vt[64][68];
    __shared__ bf16 Pt[4][32][72];   // per-wave P^T [q_local][k]

    int tid = threadIdx.x;
    int wave = tid >> 6, lane = tid & 63;
    int m = lane & 15, g = lane >> 4;

    int bh = blockIdx.y;
    size_t base = (size_t)(bh >> 3) * SEQ_LEN * QKV_STRIDE + (size_t)(bh & 7) * HEAD_DIM;
    int q0w = blockIdx.x * 128 + wave * 32;

    const float qscale = 0.125f * 1.44269504f;   // fold log2(e) -> exp2 softmax
    short8v aQ[2][2];
#pragma unroll
    for (int mt = 0; mt < 2; mt++) {
        const bf16* qp = Q + base + (size_t)(q0w + mt * 16 + m) * QKV_STRIDE + g * 8;
#pragma unroll
        for (int c = 0; c < 2; c++) {
            frag_u u;
#pragma unroll
            for (int j = 0; j < 8; j++) u.s[j] = f2bs(b2f(qp[c * 32 + j]) * qscale);
            aQ[mt][c] = u.v8;
        }
    }

    float mrow[2] = {-1e30f, -1e30f};
    float lrow[2] = {0.f, 0.f};
    float4v oacc[2][4] = {};

    int sk = tid >> 2, sd = (tid & 3) * 16;
    int vrow = tid >> 2, vcol = (tid & 3) * 16;

    const unsigned short* Ku = (const unsigned short*)(K + base);
    const unsigned short* Vg = (const unsigned short*)Vt_g +
                               (size_t)bh * 64 * SEQ_LEN + (size_t)vrow * SEQ_LEN;

    int t0 = blockIdx.z * (64 / KSPLIT);
    int t1 = t0 + 64 / KSPLIT;
    for (int t = t0; t < t1; t++) {
        int kt0 = t * 64;
        __syncthreads();
        {   // K stage (row-major)
            const unsigned short* kp = Ku + (size_t)(kt0 + sk) * QKV_STRIDE + sd;
            *(short8v*)&Ks[sk][sd]     = *(const short8v*)(kp);
            *(short8v*)&Ks[sk][sd + 8] = *(const short8v*)(kp + 8);
        }
        {   // V stage from global V^T
            frag_u u0, u1;
            u0.v8 = *(const short8v*)(Vg + kt0 + vcol);
            u1.v8 = *(const short8v*)(Vg + kt0 + vcol + 8);
            *(short4v*)&Vt[vrow][vcol]      = u0.v4[0];
            *(short4v*)&Vt[vrow][vcol + 4]  = u0.v4[1];
            *(short4v*)&Vt[vrow][vcol + 8]  = u1.v4[0];
            *(short4v*)&Vt[vrow][vcol + 12] = u1.v4[1];
        }
        __syncthreads();

        // St: per kt load K frags once, use for both m-tiles
        float4v st[2][4];
#pragma unroll
        for (int kt = 0; kt < 4; kt++) {
            short8v bK0 = *(const short8v*)&Ks[kt * 16 + m][g * 8];
            short8v bK1 = *(const short8v*)&Ks[kt * 16 + m][32 + g * 8];
#pragma unroll
            for (int mt = 0; mt < 2; mt++) {
                float4v a = {0.f, 0.f, 0.f, 0.f};
                a = __builtin_amdgcn_mfma_f32_16x16x32_bf16(bK0, aQ[mt][0], a, 0, 0, 0);
                a = __builtin_amdgcn_mfma_f32_16x16x32_bf16(bK1, aQ[mt][1], a, 0, 0, 0);
                st[mt][kt] = a;
            }
        }

        // online softmax per m-tile (exp2 domain)
#pragma unroll
        for (int mt = 0; mt < 2; mt++) {
            float tm = st[mt][0][0];
#pragma unroll
            for (int kt = 0; kt < 4; kt++)
#pragma unroll
                for (int r = 0; r < 4; r++) tm = fmaxf(tm, st[mt][kt][r]);
            tm = fmaxf(tm, __shfl_xor(tm, 16));
            tm = fmaxf(tm, __shfl_xor(tm, 32));
            float mnew = fmaxf(mrow[mt], tm);
            float alpha = exp2fast(mrow[mt] - mnew);
            mrow[mt] = mnew;

            float psum = 0.f;
#pragma unroll
            for (int kt = 0; kt < 4; kt++) {
                float p0 = exp2fast(st[mt][kt][0] - mnew);
                float p1 = exp2fast(st[mt][kt][1] - mnew);
                float p2 = exp2fast(st[mt][kt][2] - mnew);
                float p3 = exp2fast(st[mt][kt][3] - mnew);
                psum += (p0 + p1) + (p2 + p3);
                pack_u pp;
                pp.u[0] = pack_bf16(p0, p1);
                pp.u[1] = pack_bf16(p2, p3);
                *(short4v*)&Pt[wave][mt * 16 + m][kt * 16 + g * 4] = pp.v4;
            }
            lrow[mt] = lrow[mt] * alpha + psum;
#pragma unroll
            for (int dt = 0; dt < 4; dt++)
#pragma unroll
                for (int r = 0; r < 4; r++) oacc[mt][dt][r] *= alpha;
        }

        // P^T B-frags per m-tile
        short8v bP[2][2];
#pragma unroll
        for (int mt = 0; mt < 2; mt++)
#pragma unroll
            for (int c = 0; c < 2; c++)
                bP[mt][c] = *(const short8v*)&Pt[wave][mt * 16 + m][c * 32 + g * 8];

        // PV: Vt A-frags loaded once, used for both m-tiles
#pragma unroll
        for (int dt = 0; dt < 4; dt++) {
#pragma unroll
            for (int c = 0; c < 2; c++) {
                frag_u u;
                u.v4[0] = *(const short4v*)&Vt[dt * 16 + m][c * 32 + g * 8];
                u.v4[1] = *(const short4v*)&Vt[dt * 16 + m][c * 32 + g * 8 + 4];
#pragma unroll
                for (int mt = 0; mt < 2; mt++)
                    oacc[mt][dt] = __builtin_amdgcn_mfma_f32_16x16x32_bf16(u.v8, bP[mt][c], oacc[mt][dt], 0, 0, 0);
            }
        }
    }

    size_t zoff = (size_t)blockIdx.z * NUM_HEADS * BATCH + bh;
    size_t pbase = zoff * (SEQ_LEN * (size_t)HEAD_DIM);
#pragma unroll
    for (int mt = 0; mt < 2; mt++) {
        float l = lrow[mt];
        l += __shfl_xor(l, 16);
        l += __shfl_xor(l, 32);
        int q = q0w + mt * 16 + m;
        bf16* orow = Op + pbase + (size_t)q * HEAD_DIM;
#pragma unroll
        for (int dt = 0; dt < 4; dt++) {
            pack_u oo;
            oo.u[0] = pack_bf16(oacc[mt][dt][0], oacc[mt][dt][1]);
            oo.u[1] = pack_bf16(oacc[mt][dt][2], oacc[mt][dt][3]);
            *(short4v*)&orow[dt * 16 + g * 4] = oo.v4;
        }
        if (g == 0) mlout[zoff * SEQ_LEN + q] = make_float2(mrow[mt], l);
    }
}

// Merge KSPLIT=2 partials -> attention output ab [TOKENS][D_MODEL] (exp2 domain)
__global__ void attn_merge(const bf16* __restrict__ Op, const float2* __restrict__ ml,
                           bf16* __restrict__ O) {
    int i = blockIdx.x * 256 + threadIdx.x;   // over 16*4096*64
    int d = i & 63;
    int q = (i >> 6) & (SEQ_LEN - 1);
    int bh = i >> 18;
    const int HQ = NUM_HEADS * BATCH * SEQ_LEN;
    float2 a0 = ml[bh * SEQ_LEN + q];
    float2 a1 = ml[HQ + bh * SEQ_LEN + q];
    float M = fmaxf(a0.x, a1.x);
    float w0 = exp2fast(a0.x - M), w1 = exp2fast(a1.x - M);
    float inv = 1.f / (a0.y * w0 + a1.y * w1);
    const size_t NP = (size_t)HQ * HEAD_DIM;
    float o = (b2f(Op[i]) * w0 + b2f(Op[NP + i]) * w1) * inv;
    O[((size_t)((bh >> 3) * SEQ_LEN + q)) * D_MODEL + (bh & 7) * HEAD_DIM + d] = f2b(o);
}

// ------------------------------------------------------------------------------
extern "C" void kernel_launch(void* const* d_in, const int* in_sizes, int n_in,
                              void* d_out, int out_size, void* d_ws, size_t ws_size,
                              hipStream_t stream) {
    const void* x     = d_in[0];
    const void* Wq    = d_in[1];
    const void* bq    = d_in[2];
    const void* Wk    = d_in[3];
    const void* bk    = d_in[4];
    const void* Wv    = d_in[5];
    const void* bv    = d_in[6];
    const void* Wo    = d_in[7];
    const void* bo    = d_in[8];
    const void* ln1_g = d_in[9];
    const void* ln1_b = d_in[10];
    const void* ln2_g = d_in[11];
    const void* ln2_b = d_in[12];
    const void* W1    = d_in[13];
    const void* b1    = d_in[14];
    const void* W2    = d_in[15];
    const void* b2    = d_in[16];

    // ---- workspace layout ----
    char* p = (char*)d_ws;
    int* flag = (int*)p;                      p += 256;
    size_t tok_d = (size_t)TOKENS * D_MODEL;
    // region2: KSPLIT bf16 O-partials (16.8 MB) overlay x1b+hb (16.8 MB)
    char* region2 = p;                        p += 2 * tok_d * 2;
    bf16* x1b   = (bf16*)region2;                              // [TOKENS][512]
    bf16* hb    = (bf16*)(region2 + tok_d * 2);                // [TOKENS][512]
    bf16* Opart = (bf16*)region2;
    bf16*  bigA = (bf16*)p;                   p += (size_t)TOKENS * D_FF * 2;  // 33.6 MB
    bf16*  qkvb = bigA;                                   // [TOKENS][1536]
    bf16*  ab   = bigA + (size_t)TOKENS * QKV_STRIDE;     // [TOKENS][512]
    bf16*  ffb  = bigA;                                   // [TOKENS][2048]
    bf16*  Wqkvt = (bf16*)p;                  p += (size_t)QKV_STRIDE * D_MODEL * 2;
    bf16*  Wot   = (bf16*)p;                  p += (size_t)D_MODEL * D_MODEL * 2;  // contiguous
    bf16*  W1t   = (bf16*)p;                  p += (size_t)D_FF * D_MODEL * 2;
    bf16*  W2t   = (bf16*)p;                  p += (size_t)D_MODEL * D_FF * 2;
    bf16*  Vtg   = (bf16*)p;                  p += (size_t)NUM_HEADS * BATCH * HEAD_DIM * SEQ_LEN * 2;
    float2* mlb  = (float2*)p;                p += (size_t)KSPLIT * NUM_HEADS * BATCH * SEQ_LEN * sizeof(float2);
    bf16*  small = (bf16*)p;                  p += 6656 * 2;
    bf16* bias_qkv = small + 0;
    bf16* bias_o   = small + 1536;
    bf16* b1b      = small + 2048;
    bf16* b2b      = small + 4096;
    bf16* g1b      = small + 4608;
    bf16* be1b     = small + 5120;
    bf16* g2b      = small + 5632;
    bf16* be2b     = small + 6144;

    prep_kernel<<<794, 256, 0, stream>>>(x, Wq, Wk, Wv, Wo, W1, W2,
                                         bq, bk, bv, bo, b1, b2,
                                         ln1_g, ln1_b, ln2_g, ln2_b,
                                         Wqkvt, W1t, W2t, small, flag);

    // LN1 reads raw x (dtype per flag, written by prep)
    ln_kernel<2><<<TOKENS, 256, 0, stream>>>(x, g1b, be1b, hb, flag);

    // fused QKV projection
    mfma_gemm<0><<<dim3(QKV_STRIDE / 128, TOKENS / 128), 256, 0, stream>>>(
        hb, Wqkvt, bias_qkv, qkvb, TOKENS, QKV_STRIDE, D_MODEL);

    // V -> global V^T [bh][dim][seq]
    v_transpose<<<dim3(SEQ_LEN / 64, NUM_HEADS * BATCH), 256, 0, stream>>>(qkvb, Vtg);

    flash_attn<<<dim3(SEQ_LEN / 128, 16, KSPLIT), 256, 0, stream>>>(
        qkvb, qkvb + 512, Vtg, Opart, mlb);
    attn_merge<<<(NUM_HEADS * BATCH * SEQ_LEN * HEAD_DIM) / 256, 256, 0, stream>>>(
        Opart, mlb, ab);

    // O projection + residual(raw x) -> x1 (bf16); 512 blocks
    mfma_gemm64<3, 0><<<dim3(D_MODEL / 64, TOKENS / 128), 256, 0, stream>>>(
        ab, Wot, bias_o, x, x1b, flag, TOKENS, D_MODEL, D_MODEL);

    ln_kernel<0><<<TOKENS, 256, 0, stream>>>(x1b, g2b, be2b, hb, flag);

    // FFN1 + GELU
    mfma_gemm<1><<<dim3(D_FF / 128, TOKENS / 128), 256, 0, stream>>>(
        hb, W1t, b1b, ffb, TOKENS, D_FF, D_MODEL);

    // FFN2 + residual(x1 bf16) -> out (dtype per flag); 512 blocks
    mfma_gemm64<2, 2><<<dim3(D_MODEL / 64, TOKENS / 128), 256, 0, stream>>>(
        ffb, W2t, b2b, x1b, d_out, flag, TOKENS, D_MODEL, D_FF);
}